// Round 1
// baseline (5341.715 us; speedup 1.0000x reference)
//
#include <hip/hip_runtime.h>

// Problem constants
#define BROWS 16384
#define INDIM 4096
#define HID   2048
#define BOT   64
#define NC    8192

// ---------------------------------------------------------------------------
// Generic f32 tiled SGEMM: C = [relu](A @ B + bias)
// A: M x K row-major, B: K x N row-major, bias: N, C: M x N
// Block = 256 threads; per-thread TM x TN micro-tile.
// ---------------------------------------------------------------------------
template <int BM, int BN, int BK, int TM, int TN, bool RELU>
__global__ __launch_bounds__(256) void sgemm_kernel(
    const float* __restrict__ A, const float* __restrict__ B,
    const float* __restrict__ bias, float* __restrict__ C,
    int M, int N, int K) {
  static_assert((BM / TM) * (BN / TN) == 256, "block must be 256 threads");
  static_assert((BM * BK) % (4 * 256) == 0, "A tile loads");
  static_assert((BK * BN) % (4 * 256) == 0, "B tile loads");
  constexpr int PAD = 4;
  __shared__ float As[BK][BM + PAD];  // transposed: As[k][m]
  __shared__ float Bs[BK][BN + PAD];  // Bs[k][n]

  const int tid = threadIdx.x;
  const int NXT = BN / TN;            // threads along N
  const int tx = tid % NXT;
  const int ty = tid / NXT;
  const int n0 = blockIdx.x * BN;
  const int m0 = blockIdx.y * BM;

  float acc[TM][TN];
#pragma unroll
  for (int i = 0; i < TM; i++)
#pragma unroll
    for (int j = 0; j < TN; j++) acc[i][j] = 0.0f;

  constexpr int A_LOADS = BM * BK / 4 / 256;
  constexpr int B_LOADS = BK * BN / 4 / 256;

  for (int k0 = 0; k0 < K; k0 += BK) {
    // A tile (BM x BK) -> As[k][m] (transposed)
#pragma unroll
    for (int i = 0; i < A_LOADS; i++) {
      int idx = tid + i * 256;
      int row = idx / (BK / 4);
      int c4 = idx % (BK / 4);
      const float4 v = *reinterpret_cast<const float4*>(
          &A[(size_t)(m0 + row) * K + k0 + c4 * 4]);
      As[c4 * 4 + 0][row] = v.x;
      As[c4 * 4 + 1][row] = v.y;
      As[c4 * 4 + 2][row] = v.z;
      As[c4 * 4 + 3][row] = v.w;
    }
    // B tile (BK x BN) -> Bs[k][n]
#pragma unroll
    for (int i = 0; i < B_LOADS; i++) {
      int idx = tid + i * 256;
      int row = idx / (BN / 4);
      int c4 = idx % (BN / 4);
      const float4 v = *reinterpret_cast<const float4*>(
          &B[(size_t)(k0 + row) * N + n0 + c4 * 4]);
      *reinterpret_cast<float4*>(&Bs[row][c4 * 4]) = v;
    }
    __syncthreads();

#pragma unroll
    for (int k = 0; k < BK; k++) {
      float a[TM], b[TN];
#pragma unroll
      for (int i = 0; i < TM; i += 4) {
        float4 v = *reinterpret_cast<const float4*>(&As[k][ty * TM + i]);
        a[i + 0] = v.x; a[i + 1] = v.y; a[i + 2] = v.z; a[i + 3] = v.w;
      }
#pragma unroll
      for (int j = 0; j < TN; j += 4) {
        float4 v = *reinterpret_cast<const float4*>(&Bs[k][tx * TN + j]);
        b[j + 0] = v.x; b[j + 1] = v.y; b[j + 2] = v.z; b[j + 3] = v.w;
      }
#pragma unroll
      for (int i = 0; i < TM; i++)
#pragma unroll
        for (int j = 0; j < TN; j++) acc[i][j] = fmaf(a[i], b[j], acc[i][j]);
    }
    __syncthreads();
  }

  // epilogue: bias (+ relu), vectorized store
  float bv[TN];
#pragma unroll
  for (int j = 0; j < TN; j++) bv[j] = bias[n0 + tx * TN + j];
#pragma unroll
  for (int i = 0; i < TM; i++) {
#pragma unroll
    for (int j = 0; j < TN; j += 4) {
      float4 o;
      float v0 = acc[i][j + 0] + bv[j + 0];
      float v1 = acc[i][j + 1] + bv[j + 1];
      float v2 = acc[i][j + 2] + bv[j + 2];
      float v3 = acc[i][j + 3] + bv[j + 3];
      if (RELU) {
        v0 = fmaxf(v0, 0.0f); v1 = fmaxf(v1, 0.0f);
        v2 = fmaxf(v2, 0.0f); v3 = fmaxf(v3, 0.0f);
      }
      o.x = v0; o.y = v1; o.z = v2; o.w = v3;
      *reinterpret_cast<float4*>(
          &C[(size_t)(m0 + ty * TM + i) * N + n0 + tx * TN + j]) = o;
    }
  }
}

// ---------------------------------------------------------------------------
// Row squared-norm: out[r] = sum_k v[r][k]^2   (rows of width 64)
// Separate mul+add (no fma contraction) to mimic square-then-sum.
// ---------------------------------------------------------------------------
__global__ void rownorm64_kernel(const float* __restrict__ v,
                                 float* __restrict__ out, int rows) {
  int r = blockIdx.x * blockDim.x + threadIdx.x;
  if (r >= rows) return;
  const float* p = v + (size_t)r * 64;
  float s = 0.0f;
#pragma unroll 8
  for (int k = 0; k < 64; k++) {
    float q = __fmul_rn(p[k], p[k]);
    s = __fadd_rn(s, q);
  }
  out[r] = s;
}

// ---------------------------------------------------------------------------
// VQ argmin: per row, d_j = (zn[r] + cn[j]) - 2 * <z_e[r], c[j]>, argmin_j
// Block handles 64 rows; loops over all 8192 codes in tiles of 64.
// First-occurrence tie-breaking (smaller index wins on equal distance).
// ---------------------------------------------------------------------------
__global__ __launch_bounds__(256) void vq_argmin_kernel(
    const float* __restrict__ z_e, const float* __restrict__ cb,
    const float* __restrict__ zn, const float* __restrict__ cn,
    int* __restrict__ out_idx) {
  __shared__ float Zs[64][68];  // [k][row]
  __shared__ float Cs[64][68];  // [k][code]
  __shared__ float CNs[64];

  const int tid = threadIdx.x;
  const int r0 = blockIdx.x * 64;
  const int tx = tid & 15;   // code group
  const int ty = tid >> 4;   // row group (0..15)

  // stage z_e rows transposed
#pragma unroll
  for (int i = 0; i < 4; i++) {
    int idx = tid + i * 256;
    int row = idx >> 4;
    int c4 = idx & 15;
    float4 v = *reinterpret_cast<const float4*>(
        &z_e[(size_t)(r0 + row) * 64 + c4 * 4]);
    Zs[c4 * 4 + 0][row] = v.x;
    Zs[c4 * 4 + 1][row] = v.y;
    Zs[c4 * 4 + 2][row] = v.z;
    Zs[c4 * 4 + 3][row] = v.w;
  }
  float myzn[4];
#pragma unroll
  for (int i = 0; i < 4; i++) myzn[i] = zn[r0 + ty * 4 + i];

  float best[4];
  int bidx[4];
#pragma unroll
  for (int i = 0; i < 4; i++) {
    best[i] = 3.402823466e38f;
    bidx[i] = 0;
  }
  __syncthreads();

  for (int c0 = 0; c0 < NC; c0 += 64) {
    // stage codebook tile transposed
#pragma unroll
    for (int i = 0; i < 4; i++) {
      int idx = tid + i * 256;
      int row = idx >> 4;
      int c4 = idx & 15;
      float4 v = *reinterpret_cast<const float4*>(
          &cb[(size_t)(c0 + row) * 64 + c4 * 4]);
      Cs[c4 * 4 + 0][row] = v.x;
      Cs[c4 * 4 + 1][row] = v.y;
      Cs[c4 * 4 + 2][row] = v.z;
      Cs[c4 * 4 + 3][row] = v.w;
    }
    if (tid < 64) CNs[tid] = cn[c0 + tid];
    __syncthreads();

    float dot[4][4];
#pragma unroll
    for (int i = 0; i < 4; i++)
#pragma unroll
      for (int j = 0; j < 4; j++) dot[i][j] = 0.0f;

#pragma unroll 4
    for (int k = 0; k < 64; k++) {
      float4 av = *reinterpret_cast<const float4*>(&Zs[k][ty * 4]);
      float4 bv = *reinterpret_cast<const float4*>(&Cs[k][tx * 4]);
      float a[4] = {av.x, av.y, av.z, av.w};
      float b[4] = {bv.x, bv.y, bv.z, bv.w};
#pragma unroll
      for (int i = 0; i < 4; i++)
#pragma unroll
        for (int j = 0; j < 4; j++) dot[i][j] = fmaf(a[i], b[j], dot[i][j]);
    }

#pragma unroll
    for (int i = 0; i < 4; i++)
#pragma unroll
      for (int j = 0; j < 4; j++) {
        float t = __fadd_rn(myzn[i], CNs[tx * 4 + j]);
        float d = __fadd_rn(t, -2.0f * dot[i][j]);
        int c = c0 + tx * 4 + j;
        if (d < best[i] || (d == best[i] && c < bidx[i])) {
          best[i] = d;
          bidx[i] = c;
        }
      }
    __syncthreads();
  }

  // reduce across the 16 tx lanes (same ty) within the wave
#pragma unroll
  for (int m = 1; m < 16; m <<= 1) {
#pragma unroll
    for (int i = 0; i < 4; i++) {
      float ov = __shfl_xor(best[i], m, 64);
      int oi = __shfl_xor(bidx[i], m, 64);
      if (ov < best[i] || (ov == best[i] && oi < bidx[i])) {
        best[i] = ov;
        bidx[i] = oi;
      }
    }
  }
  if (tx == 0) {
#pragma unroll
    for (int i = 0; i < 4; i++) out_idx[r0 + ty * 4 + i] = bidx[i];
  }
}

// ---------------------------------------------------------------------------
// Gather z output: out0[r] = z_e[r] + (codebook[idx[r]] - z_e[r])  (f32, mimics
// the reference's straight-through rounding)
// ---------------------------------------------------------------------------
__global__ void gather_z_kernel(const float* __restrict__ z_e,
                                const float* __restrict__ cb,
                                const int* __restrict__ idx,
                                float* __restrict__ out0) {
  int t = blockIdx.x * 256 + threadIdx.x;
  int row = t >> 4;
  int c4 = t & 15;
  int code = idx[row];
  float4 q = *reinterpret_cast<const float4*>(&cb[(size_t)code * 64 + c4 * 4]);
  float4 e = *reinterpret_cast<const float4*>(&z_e[(size_t)row * 64 + c4 * 4]);
  float4 o;
  o.x = __fadd_rn(e.x, __fsub_rn(q.x, e.x));
  o.y = __fadd_rn(e.y, __fsub_rn(q.y, e.y));
  o.z = __fadd_rn(e.z, __fsub_rn(q.z, e.z));
  o.w = __fadd_rn(e.w, __fsub_rn(q.w, e.w));
  *reinterpret_cast<float4*>(&out0[(size_t)row * 64 + c4 * 4]) = o;
}

// ---------------------------------------------------------------------------
// Gather reconstruction: out1[r] = table[idx[r]]  (row of 4096 f32)
// ---------------------------------------------------------------------------
__global__ void gather_recon_kernel(const float* __restrict__ table,
                                    const int* __restrict__ idx,
                                    float* __restrict__ out1) {
  int row = blockIdx.x >> 2;
  int q = blockIdx.x & 3;
  int c4 = q * 256 + threadIdx.x;  // 0..1023 float4 per row
  int code = idx[row];
  float4 v = *reinterpret_cast<const float4*>(
      &table[(size_t)code * 4096 + (size_t)c4 * 4]);
  *reinterpret_cast<float4*>(&out1[(size_t)row * 4096 + (size_t)c4 * 4]) = v;
}

// ---------------------------------------------------------------------------
extern "C" void kernel_launch(void* const* d_in, const int* in_sizes, int n_in,
                              void* d_out, int out_size, void* d_ws,
                              size_t ws_size, hipStream_t stream) {
  const float* x   = (const float*)d_in[0];
  const float* W1  = (const float*)d_in[1];
  const float* b1  = (const float*)d_in[2];
  const float* W2  = (const float*)d_in[3];
  const float* b2  = (const float*)d_in[4];
  const float* cb  = (const float*)d_in[5];
  const float* dW1 = (const float*)d_in[6];
  const float* db1 = (const float*)d_in[7];
  const float* dW2 = (const float*)d_in[8];
  const float* db2 = (const float*)d_in[9];

  float* out0 = (float*)d_out;                       // z: 16384 x 64
  float* out1 = out0 + (size_t)BROWS * BOT;          // x_recon: 16384 x 4096

  // Scratch inside the (not-yet-final) out1 region: h then ht; both dead
  // before the final gathers overwrite out1.
  float* h  = out1;                                  // 16384 x 2048 (128 MB)
  float* ht = out1 + (size_t)BROWS * HID;            // 8192 x 2048  (64 MB)

  char* ws = (char*)d_ws;
  float* table = (float*)ws;                         // 8192 x 4096 (128 MB)
  float* z_e   = (float*)(ws + 134217728);           // 16384 x 64 (4 MB)
  float* zn    = (float*)(ws + 138412032);           // 16384
  float* cn    = (float*)(ws + 138477568);           // 8192
  int*   idxb  = (int*)(ws + 138510336);             // 16384

  dim3 blk(256);

  // 1. h = relu(x @ W1 + b1)        M=16384 N=2048 K=4096
  sgemm_kernel<128, 128, 16, 8, 8, true>
      <<<dim3(HID / 128, BROWS / 128), blk, 0, stream>>>(x, W1, b1, h, BROWS,
                                                         HID, INDIM);
  // 2. z_e = h @ W2 + b2            M=16384 N=64 K=2048
  sgemm_kernel<64, 64, 32, 4, 4, false>
      <<<dim3(1, BROWS / 64), blk, 0, stream>>>(h, W2, b2, z_e, BROWS, BOT,
                                                HID);
  // 3. norms
  rownorm64_kernel<<<dim3(BROWS / 256), blk, 0, stream>>>(z_e, zn, BROWS);
  rownorm64_kernel<<<dim3(NC / 256), blk, 0, stream>>>(cb, cn, NC);
  // 4. argmin over codes
  vq_argmin_kernel<<<dim3(BROWS / 64), blk, 0, stream>>>(z_e, cb, zn, cn,
                                                         idxb);
  // 5. ht = relu(codebook @ dW1 + db1)   M=8192 N=2048 K=64
  sgemm_kernel<128, 128, 16, 8, 8, true>
      <<<dim3(HID / 128, NC / 128), blk, 0, stream>>>(cb, dW1, db1, ht, NC,
                                                      HID, BOT);
  // 6. table = ht @ dW2 + db2            M=8192 N=4096 K=2048
  sgemm_kernel<128, 128, 16, 8, 8, false>
      <<<dim3(INDIM / 128, NC / 128), blk, 0, stream>>>(ht, dW2, db2, table,
                                                        NC, INDIM, HID);
  // 7. z output
  gather_z_kernel<<<dim3(BROWS * 16 / 256), blk, 0, stream>>>(z_e, cb, idxb,
                                                              out0);
  // 8. x_recon output
  gather_recon_kernel<<<dim3(BROWS * 4), blk, 0, stream>>>(table, idxb, out1);
}

// Round 2
// 1858.532 us; speedup vs baseline: 2.8742x; 2.8742x over previous
//
#include <hip/hip_runtime.h>
#include <hip/hip_bf16.h>

// Problem constants
#define BROWS 16384
#define INDIM 4096
#define HID   2048
#define BOT   64
#define NC    8192

typedef __hip_bfloat16 bf16;
typedef __attribute__((ext_vector_type(8))) short bf16x8;
typedef __attribute__((ext_vector_type(4))) float f32x4;

// ---------------------------------------------------------------------------
// Split-bf16 MFMA GEMM: C = [relu]( (Ah+Al) @ (Bh+Bl)^T + bias ), dropping
// the Al*Bl term (~2^-18 relative). A*: M x K row-major bf16 (hi/lo).
// B*: N x K row-major bf16 (i.e. B transposed; hi/lo). C: M x N f32.
// 256 threads = 4 waves; 128x128 tile; BK=64; 16x16x32 bf16 MFMA.
// LDS: 4 matrices x 128 rows x 64 bf16 (128 B/row), XOR-swizzled chunks.
// ---------------------------------------------------------------------------
template <bool RELU>
__global__ __launch_bounds__(256, 2) void mfma_split_gemm(
    const bf16* __restrict__ Ah, const bf16* __restrict__ Al,
    const bf16* __restrict__ Bh, const bf16* __restrict__ Bl,
    const float* __restrict__ bias, float* __restrict__ C,
    int M, int N, int K) {
  __shared__ __align__(16) short sm[4 * 128 * 64];  // 64 KB: Ah|Al|Bh|Bl

  const int tid = threadIdx.x;
  const int lane = tid & 63;
  const int w = tid >> 6;
  const int wr = w >> 1, wc = w & 1;   // wave 64x64 sub-tile
  const int m0 = blockIdx.y * 128;
  const int n0 = blockIdx.x * 128;

  const bf16* Gm[4] = {Ah + (size_t)m0 * K, Al + (size_t)m0 * K,
                       Bh + (size_t)n0 * K, Bl + (size_t)n0 * K};

  f32x4 acc[4][4] = {};

  for (int kt = 0; kt < K; kt += 64) {
    // ---- stage 4 x (128 x 64 bf16) tiles via global_load_lds (16B/lane) ----
#pragma unroll
    for (int i = 0; i < 16; i++) {
      const int mat = i >> 2;
      const int j = i & 3;
      const int cb = j * 256 + w * 64;       // wave-uniform chunk base
      const int c = cb + lane;               // 16B-chunk index in tile
      const int r = c >> 3;                  // tile row (0..127)
      const int kcg = (c & 7) ^ (r & 7);     // inverse-swizzled global chunk
      const bf16* src = Gm[mat] + (size_t)r * K + kt + kcg * 8;
      const short* ld = sm + mat * 8192 + cb * 8;  // linear LDS dest
      uint32_t m0v = __builtin_amdgcn_readfirstlane((uint32_t)(uintptr_t)ld);
      asm volatile("s_mov_b32 m0, %0\n\t"
                   "global_load_lds_dwordx4 %1, off\n\t"
                   :: "s"(m0v), "v"(src) : "memory");
    }
    asm volatile("s_waitcnt vmcnt(0)" ::: "memory");
    __syncthreads();

    // ---- 2 k-steps of 32; 48 MFMA each (3-term split) ----
#pragma unroll
    for (int s = 0; s < 2; s++) {
      bf16x8 ah[4], al[4];
#pragma unroll
      for (int mi = 0; mi < 4; mi++) {
        const int p = wr * 64 + mi * 16 + (lane & 15);
        const int ch = (s * 4 + (lane >> 4)) ^ (p & 7);
        ah[mi] = *(const bf16x8*)(sm + p * 64 + ch * 8);
        al[mi] = *(const bf16x8*)(sm + 8192 + p * 64 + ch * 8);
      }
#pragma unroll
      for (int ni = 0; ni < 4; ni++) {
        const int q = wc * 64 + ni * 16 + (lane & 15);
        const int ch = (s * 4 + (lane >> 4)) ^ (q & 7);
        bf16x8 bh = *(const bf16x8*)(sm + 16384 + q * 64 + ch * 8);
        bf16x8 bl = *(const bf16x8*)(sm + 24576 + q * 64 + ch * 8);
#pragma unroll
        for (int mi = 0; mi < 4; mi++) {
          acc[mi][ni] = __builtin_amdgcn_mfma_f32_16x16x32_bf16(
              ah[mi], bh, acc[mi][ni], 0, 0, 0);
          acc[mi][ni] = __builtin_amdgcn_mfma_f32_16x16x32_bf16(
              ah[mi], bl, acc[mi][ni], 0, 0, 0);
          acc[mi][ni] = __builtin_amdgcn_mfma_f32_16x16x32_bf16(
              al[mi], bh, acc[mi][ni], 0, 0, 0);
        }
      }
    }
    __syncthreads();
  }

  // ---- epilogue: bias (+relu), C/D layout col=lane&15, row=(lane>>4)*4+r ----
  const int colb = n0 + wc * 64 + (lane & 15);
  const int rowb = m0 + wr * 64 + ((lane >> 4) << 2);
#pragma unroll
  for (int ni = 0; ni < 4; ni++) {
    const float bv = bias[colb + ni * 16];
#pragma unroll
    for (int mi = 0; mi < 4; mi++) {
#pragma unroll
      for (int r = 0; r < 4; r++) {
        float v = acc[mi][ni][r] + bv;
        if (RELU) v = fmaxf(v, 0.0f);
        C[(size_t)(rowb + mi * 16 + r) * N + colb + ni * 16] = v;
      }
    }
  }
}

// ---------------------------------------------------------------------------
// f32 tiled SGEMM (round-1 version, kept for the small GEMMs)
// ---------------------------------------------------------------------------
template <int BM, int BN, int BK, int TM, int TN, bool RELU>
__global__ __launch_bounds__(256) void sgemm_kernel(
    const float* __restrict__ A, const float* __restrict__ B,
    const float* __restrict__ bias, float* __restrict__ C,
    int M, int N, int K) {
  static_assert((BM / TM) * (BN / TN) == 256, "block must be 256 threads");
  constexpr int PAD = 4;
  __shared__ float As[BK][BM + PAD];
  __shared__ float Bs[BK][BN + PAD];

  const int tid = threadIdx.x;
  const int NXT = BN / TN;
  const int tx = tid % NXT;
  const int ty = tid / NXT;
  const int n0 = blockIdx.x * BN;
  const int m0 = blockIdx.y * BM;

  float acc[TM][TN];
#pragma unroll
  for (int i = 0; i < TM; i++)
#pragma unroll
    for (int j = 0; j < TN; j++) acc[i][j] = 0.0f;

  constexpr int A_LOADS = BM * BK / 4 / 256;
  constexpr int B_LOADS = BK * BN / 4 / 256;

  for (int k0 = 0; k0 < K; k0 += BK) {
#pragma unroll
    for (int i = 0; i < A_LOADS; i++) {
      int idx = tid + i * 256;
      int row = idx / (BK / 4);
      int c4 = idx % (BK / 4);
      const float4 v = *reinterpret_cast<const float4*>(
          &A[(size_t)(m0 + row) * K + k0 + c4 * 4]);
      As[c4 * 4 + 0][row] = v.x;
      As[c4 * 4 + 1][row] = v.y;
      As[c4 * 4 + 2][row] = v.z;
      As[c4 * 4 + 3][row] = v.w;
    }
#pragma unroll
    for (int i = 0; i < B_LOADS; i++) {
      int idx = tid + i * 256;
      int row = idx / (BN / 4);
      int c4 = idx % (BN / 4);
      const float4 v = *reinterpret_cast<const float4*>(
          &B[(size_t)(k0 + row) * N + n0 + c4 * 4]);
      *reinterpret_cast<float4*>(&Bs[row][c4 * 4]) = v;
    }
    __syncthreads();

#pragma unroll
    for (int k = 0; k < BK; k++) {
      float a[TM], b[TN];
#pragma unroll
      for (int i = 0; i < TM; i += 4) {
        float4 v = *reinterpret_cast<const float4*>(&As[k][ty * TM + i]);
        a[i + 0] = v.x; a[i + 1] = v.y; a[i + 2] = v.z; a[i + 3] = v.w;
      }
#pragma unroll
      for (int j = 0; j < TN; j += 4) {
        float4 v = *reinterpret_cast<const float4*>(&Bs[k][tx * TN + j]);
        b[j + 0] = v.x; b[j + 1] = v.y; b[j + 2] = v.z; b[j + 3] = v.w;
      }
#pragma unroll
      for (int i = 0; i < TM; i++)
#pragma unroll
        for (int j = 0; j < TN; j++) acc[i][j] = fmaf(a[i], b[j], acc[i][j]);
    }
    __syncthreads();
  }

  float bv[TN];
#pragma unroll
  for (int j = 0; j < TN; j++) bv[j] = bias[n0 + tx * TN + j];
#pragma unroll
  for (int i = 0; i < TM; i++) {
#pragma unroll
    for (int j = 0; j < TN; j += 4) {
      float4 o;
      float v0 = acc[i][j + 0] + bv[j + 0];
      float v1 = acc[i][j + 1] + bv[j + 1];
      float v2 = acc[i][j + 2] + bv[j + 2];
      float v3 = acc[i][j + 3] + bv[j + 3];
      if (RELU) {
        v0 = fmaxf(v0, 0.0f); v1 = fmaxf(v1, 0.0f);
        v2 = fmaxf(v2, 0.0f); v3 = fmaxf(v3, 0.0f);
      }
      o.x = v0; o.y = v1; o.z = v2; o.w = v3;
      *reinterpret_cast<float4*>(
          &C[(size_t)(m0 + ty * TM + i) * N + n0 + tx * TN + j]) = o;
    }
  }
}

// ---------------------------------------------------------------------------
// f32 -> (bf16 hi, bf16 lo) elementwise split, 4 elems/thread
// ---------------------------------------------------------------------------
__global__ void split_kernel(const float* __restrict__ src,
                             bf16* __restrict__ dh, bf16* __restrict__ dl,
                             long n4) {
  long i = (long)blockIdx.x * 256 + threadIdx.x;
  if (i >= n4) return;
  float4 v = ((const float4*)src)[i];
  float a[4] = {v.x, v.y, v.z, v.w};
  ushort h[4], l[4];
#pragma unroll
  for (int c = 0; c < 4; c++) {
    bf16 hb = __float2bfloat16(a[c]);
    float hf = __bfloat162float(hb);
    bf16 lb = __float2bfloat16(a[c] - hf);
    h[c] = *(ushort*)&hb;
    l[c] = *(ushort*)&lb;
  }
  ((ushort4*)dh)[i] = make_ushort4(h[0], h[1], h[2], h[3]);
  ((ushort4*)dl)[i] = make_ushort4(l[0], l[1], l[2], l[3]);
}

// ---------------------------------------------------------------------------
// Transposing split: src (R x C f32) -> dh, dl (C x R bf16)
// ---------------------------------------------------------------------------
__global__ __launch_bounds__(256) void transpose_split_kernel(
    const float* __restrict__ src, bf16* __restrict__ dh,
    bf16* __restrict__ dl, int R, int C) {
  __shared__ float t[32][33];
  const int c0 = blockIdx.x * 32, r0 = blockIdx.y * 32;
  const int tx = threadIdx.x & 31, ty = threadIdx.x >> 5;  // ty 0..7
#pragma unroll
  for (int i = 0; i < 32; i += 8)
    t[ty + i][tx] = src[(size_t)(r0 + ty + i) * C + c0 + tx];
  __syncthreads();
#pragma unroll
  for (int i = 0; i < 32; i += 8) {
    float v = t[tx][ty + i];
    bf16 hb = __float2bfloat16(v);
    float hf = __bfloat162float(hb);
    bf16 lb = __float2bfloat16(v - hf);
    dh[(size_t)(c0 + ty + i) * R + r0 + tx] = hb;
    dl[(size_t)(c0 + ty + i) * R + r0 + tx] = lb;
  }
}

// ---------------------------------------------------------------------------
// Row squared-norm (rows of width 64), mul+add to mimic square-then-sum
// ---------------------------------------------------------------------------
__global__ void rownorm64_kernel(const float* __restrict__ v,
                                 float* __restrict__ out, int rows) {
  int r = blockIdx.x * blockDim.x + threadIdx.x;
  if (r >= rows) return;
  const float* p = v + (size_t)r * 64;
  float s = 0.0f;
#pragma unroll 8
  for (int k = 0; k < 64; k++) {
    float q = __fmul_rn(p[k], p[k]);
    s = __fadd_rn(s, q);
  }
  out[r] = s;
}

// ---------------------------------------------------------------------------
// VQ argmin (round-1 version, verified)
// ---------------------------------------------------------------------------
__global__ __launch_bounds__(256) void vq_argmin_kernel(
    const float* __restrict__ z_e, const float* __restrict__ cb,
    const float* __restrict__ zn, const float* __restrict__ cn,
    int* __restrict__ out_idx) {
  __shared__ float Zs[64][68];
  __shared__ float Cs[64][68];
  __shared__ float CNs[64];

  const int tid = threadIdx.x;
  const int r0 = blockIdx.x * 64;
  const int tx = tid & 15;
  const int ty = tid >> 4;

#pragma unroll
  for (int i = 0; i < 4; i++) {
    int idx = tid + i * 256;
    int row = idx >> 4;
    int c4 = idx & 15;
    float4 v = *reinterpret_cast<const float4*>(
        &z_e[(size_t)(r0 + row) * 64 + c4 * 4]);
    Zs[c4 * 4 + 0][row] = v.x;
    Zs[c4 * 4 + 1][row] = v.y;
    Zs[c4 * 4 + 2][row] = v.z;
    Zs[c4 * 4 + 3][row] = v.w;
  }
  float myzn[4];
#pragma unroll
  for (int i = 0; i < 4; i++) myzn[i] = zn[r0 + ty * 4 + i];

  float best[4];
  int bidx[4];
#pragma unroll
  for (int i = 0; i < 4; i++) {
    best[i] = 3.402823466e38f;
    bidx[i] = 0;
  }
  __syncthreads();

  for (int c0 = 0; c0 < NC; c0 += 64) {
#pragma unroll
    for (int i = 0; i < 4; i++) {
      int idx = tid + i * 256;
      int row = idx >> 4;
      int c4 = idx & 15;
      float4 v = *reinterpret_cast<const float4*>(
          &cb[(size_t)(c0 + row) * 64 + c4 * 4]);
      Cs[c4 * 4 + 0][row] = v.x;
      Cs[c4 * 4 + 1][row] = v.y;
      Cs[c4 * 4 + 2][row] = v.z;
      Cs[c4 * 4 + 3][row] = v.w;
    }
    if (tid < 64) CNs[tid] = cn[c0 + tid];
    __syncthreads();

    float dot[4][4];
#pragma unroll
    for (int i = 0; i < 4; i++)
#pragma unroll
      for (int j = 0; j < 4; j++) dot[i][j] = 0.0f;

#pragma unroll 4
    for (int k = 0; k < 64; k++) {
      float4 av = *reinterpret_cast<const float4*>(&Zs[k][ty * 4]);
      float4 bv = *reinterpret_cast<const float4*>(&Cs[k][tx * 4]);
      float a[4] = {av.x, av.y, av.z, av.w};
      float b[4] = {bv.x, bv.y, bv.z, bv.w};
#pragma unroll
      for (int i = 0; i < 4; i++)
#pragma unroll
        for (int j = 0; j < 4; j++) dot[i][j] = fmaf(a[i], b[j], dot[i][j]);
    }

#pragma unroll
    for (int i = 0; i < 4; i++)
#pragma unroll
      for (int j = 0; j < 4; j++) {
        float t = __fadd_rn(myzn[i], CNs[tx * 4 + j]);
        float d = __fadd_rn(t, -2.0f * dot[i][j]);
        int c = c0 + tx * 4 + j;
        if (d < best[i] || (d == best[i] && c < bidx[i])) {
          best[i] = d;
          bidx[i] = c;
        }
      }
    __syncthreads();
  }

#pragma unroll
  for (int m = 1; m < 16; m <<= 1) {
#pragma unroll
    for (int i = 0; i < 4; i++) {
      float ov = __shfl_xor(best[i], m, 64);
      int oi = __shfl_xor(bidx[i], m, 64);
      if (ov < best[i] || (ov == best[i] && oi < bidx[i])) {
        best[i] = ov;
        bidx[i] = oi;
      }
    }
  }
  if (tx == 0) {
#pragma unroll
    for (int i = 0; i < 4; i++) out_idx[r0 + ty * 4 + i] = bidx[i];
  }
}

// ---------------------------------------------------------------------------
// z output (in-place safe: each thread reads then writes its own float4)
// ---------------------------------------------------------------------------
__global__ void gather_z_kernel(const float* __restrict__ z_e,
                                const float* __restrict__ cb,
                                const int* __restrict__ idx,
                                float* __restrict__ out0) {
  int t = blockIdx.x * 256 + threadIdx.x;
  int row = t >> 4;
  int c4 = t & 15;
  int code = idx[row];
  float4 q = *reinterpret_cast<const float4*>(&cb[(size_t)code * 64 + c4 * 4]);
  float4 e = *reinterpret_cast<const float4*>(&z_e[(size_t)row * 64 + c4 * 4]);
  float4 o;
  o.x = __fadd_rn(e.x, __fsub_rn(q.x, e.x));
  o.y = __fadd_rn(e.y, __fsub_rn(q.y, e.y));
  o.z = __fadd_rn(e.z, __fsub_rn(q.z, e.z));
  o.w = __fadd_rn(e.w, __fsub_rn(q.w, e.w));
  *reinterpret_cast<float4*>(&out0[(size_t)row * 64 + c4 * 4]) = o;
}

__global__ void gather_recon_kernel(const float* __restrict__ table,
                                    const int* __restrict__ idx,
                                    float* __restrict__ out1) {
  int row = blockIdx.x >> 2;
  int q = blockIdx.x & 3;
  int c4 = q * 256 + threadIdx.x;
  int code = idx[row];
  float4 v = *reinterpret_cast<const float4*>(
      &table[(size_t)code * 4096 + (size_t)c4 * 4]);
  *reinterpret_cast<float4*>(&out1[(size_t)row * 4096 + (size_t)c4 * 4]) = v;
}

// ---------------------------------------------------------------------------
extern "C" void kernel_launch(void* const* d_in, const int* in_sizes, int n_in,
                              void* d_out, int out_size, void* d_ws,
                              size_t ws_size, hipStream_t stream) {
  const float* x   = (const float*)d_in[0];
  const float* W1  = (const float*)d_in[1];
  const float* b1  = (const float*)d_in[2];
  const float* W2  = (const float*)d_in[3];
  const float* b2  = (const float*)d_in[4];
  const float* cb  = (const float*)d_in[5];
  const float* dW1 = (const float*)d_in[6];
  const float* db1 = (const float*)d_in[7];
  const float* dW2 = (const float*)d_in[8];
  const float* db2 = (const float*)d_in[9];

  float* out0 = (float*)d_out;                        // z: 16384 x 64 (4 MB)
  float* out1 = out0 + (size_t)BROWS * BOT;           // x_recon region (256 MB)

  // out1 region reuse:
  bf16* xh = (bf16*)out1;                             // [0,128 MB)
  bf16* xl = (bf16*)((char*)out1 + (size_t)(128 << 20));  // [128,256 MB)
  // decoder phase (xh/xl dead by then):
  float* htf  = out1;                                            // [0,64)
  bf16* hth   = (bf16*)((char*)out1 + (size_t)(64 << 20));       // [64,96)
  bf16* htl   = (bf16*)((char*)out1 + (size_t)(96 << 20));       // [96,128)
  bf16* dW2th = (bf16*)((char*)out1 + (size_t)(128 << 20));      // [128,144)
  bf16* dW2tl = (bf16*)((char*)out1 + (size_t)(144 << 20));      // [144,160)

  // workspace (high-water ~128.2 MB):
  char* wsb = (char*)d_ws;
  bf16* W1th  = (bf16*)wsb;                                      // [0,16)
  bf16* W1tl  = (bf16*)(wsb + (size_t)(16 << 20));               // [16,32)
  float* hbuf = (float*)(wsb + (size_t)(32 << 20));              // [32,96)
  float* table = (float*)wsb;                                    // [0,128) later
  float* zn = (float*)(wsb + (size_t)(128 << 20));
  float* cn = (float*)(wsb + (size_t)(128 << 20) + 65536);
  int* idxb = (int*)(wsb + (size_t)(128 << 20) + 65536 + 32768);

  dim3 blk(256);

  // 1. split x -> xh, xl
  split_kernel<<<dim3((BROWS * (long)INDIM) / 4 / 256), blk, 0, stream>>>(
      x, xh, xl, (BROWS * (long)INDIM) / 4);
  // 2. W1 (4096x2048) -> W1t hi/lo (2048x4096)
  transpose_split_kernel<<<dim3(HID / 32, INDIM / 32), blk, 0, stream>>>(
      W1, W1th, W1tl, INDIM, HID);

  // 3-6. GEMM1 (split-bf16 MFMA) + GEMM2 (f32), two M-halves
  for (int half = 0; half < 2; half++) {
    const size_t rowoff = (size_t)half * 8192;
    mfma_split_gemm<true><<<dim3(HID / 128, 8192 / 128), blk, 0, stream>>>(
        xh + rowoff * INDIM, xl + rowoff * INDIM, W1th, W1tl, b1, hbuf,
        8192, HID, INDIM);
    sgemm_kernel<64, 64, 32, 4, 4, false>
        <<<dim3(1, 8192 / 64), blk, 0, stream>>>(hbuf, W2, b2,
                                                 out0 + rowoff * BOT, 8192,
                                                 BOT, HID);
  }

  // 7. norms
  rownorm64_kernel<<<dim3(BROWS / 256), blk, 0, stream>>>(out0, zn, BROWS);
  rownorm64_kernel<<<dim3(NC / 256), blk, 0, stream>>>(cb, cn, NC);
  // 8. argmin
  vq_argmin_kernel<<<dim3(BROWS / 64), blk, 0, stream>>>(out0, cb, zn, cn,
                                                         idxb);

  // 9. ht = relu(codebook @ dW1 + db1)  (f32, K=64)
  sgemm_kernel<128, 128, 16, 8, 8, true>
      <<<dim3(HID / 128, NC / 128), blk, 0, stream>>>(cb, dW1, db1, htf, NC,
                                                      HID, BOT);
  // 10. split ht -> hth, htl
  split_kernel<<<dim3((NC * (long)HID) / 4 / 256), blk, 0, stream>>>(
      htf, hth, htl, (NC * (long)HID) / 4);
  // 11. dW2 (2048x4096) -> dW2t hi/lo (4096x2048)
  transpose_split_kernel<<<dim3(INDIM / 32, HID / 32), blk, 0, stream>>>(
      dW2, dW2th, dW2tl, HID, INDIM);
  // 12. table = ht @ dW2 + db2 (split-bf16 MFMA)
  mfma_split_gemm<false><<<dim3(INDIM / 128, NC / 128), blk, 0, stream>>>(
      hth, htl, dW2th, dW2tl, db2, table, NC, INDIM, HID);

  // 13. z output (in-place on out0)
  gather_z_kernel<<<dim3(BROWS * 16 / 256), blk, 0, stream>>>(out0, cb, idxb,
                                                              out0);
  // 14. x_recon output
  gather_recon_kernel<<<dim3(BROWS * 4), blk, 0, stream>>>(table, idxb, out1);
}

// Round 3
// 768.149 us; speedup vs baseline: 6.9540x; 2.4195x over previous
//
#include <hip/hip_runtime.h>
#include <hip/hip_bf16.h>

// Problem constants
#define BROWS 16384
#define INDIM 4096
#define HID   2048
#define BOT   64
#define NC    8192

typedef __hip_bfloat16 bf16;
typedef __attribute__((ext_vector_type(8))) short bf16x8;
typedef __attribute__((ext_vector_type(4))) float f32x4;

#define MB (1048576L)

// ---------------------------------------------------------------------------
// bf16 MFMA GEMM: C = [relu](A @ B^T + bias). A: M x K row-major bf16.
// B: N x K row-major bf16 (transposed operand). Outputs f32 and/or bf16.
// 256 threads = 4 waves; BM x BN tile; BK=64; 16x16x32 bf16 MFMA.
// LDS XOR-swizzled 16B chunks (verified structure from round 2).
// ---------------------------------------------------------------------------
template <int BM, int BN, int WR, int WC, bool RELU, bool WF32, bool WB16>
__global__ __launch_bounds__(256, 3) void gemm_bt(
    const ushort* __restrict__ A, const ushort* __restrict__ B,
    const float* __restrict__ bias, float* __restrict__ Cf,
    ushort* __restrict__ Cb, int M, int N, int K) {
  constexpr int FM = (BM / WR) / 16;
  constexpr int FN = (BN / WC) / 16;
  __shared__ __align__(16) short sm[(BM + BN) * 64];

  const int tid = threadIdx.x;
  const int lane = tid & 63;
  const int w = tid >> 6;
  const int wr = w / WC, wc = w % WC;

  // XCD-aware bijective swizzle (all our grids are %8==0)
  const int nwg = gridDim.x * gridDim.y;
  int bid = blockIdx.y * gridDim.x + blockIdx.x;
  if ((nwg & 7) == 0) bid = (bid & 7) * (nwg >> 3) + (bid >> 3);
  const int bx = bid % gridDim.x, by = bid / gridDim.x;
  const int m0 = by * BM, n0 = bx * BN;

  const ushort* Ag = A + (size_t)m0 * K;
  const ushort* Bg = B + (size_t)n0 * K;

  f32x4 acc[FM][FN] = {};

  for (int kt = 0; kt < K; kt += 64) {
    // stage A tile (BM x 64) + B tile (BN x 64), 16B/lane, swizzled source
#pragma unroll
    for (int j = 0; j < BM / 32; j++) {
      const int cb = j * 256 + w * 64;
      const int c = cb + lane;
      const int r = c >> 3;
      const int kc = (c & 7) ^ (r & 7);
      const ushort* src = Ag + (size_t)r * K + kt + kc * 8;
      const short* ld = sm + cb * 8;
      uint32_t m0v = __builtin_amdgcn_readfirstlane((uint32_t)(uintptr_t)ld);
      asm volatile("s_mov_b32 m0, %0\n\t"
                   "global_load_lds_dwordx4 %1, off\n\t"
                   :: "s"(m0v), "v"(src) : "memory");
    }
#pragma unroll
    for (int j = 0; j < BN / 32; j++) {
      const int cb = j * 256 + w * 64;
      const int c = cb + lane;
      const int r = c >> 3;
      const int kc = (c & 7) ^ (r & 7);
      const ushort* src = Bg + (size_t)r * K + kt + kc * 8;
      const short* ld = sm + (BM * 8 + cb) * 8;
      uint32_t m0v = __builtin_amdgcn_readfirstlane((uint32_t)(uintptr_t)ld);
      asm volatile("s_mov_b32 m0, %0\n\t"
                   "global_load_lds_dwordx4 %1, off\n\t"
                   :: "s"(m0v), "v"(src) : "memory");
    }
    asm volatile("s_waitcnt vmcnt(0)" ::: "memory");
    __syncthreads();

#pragma unroll
    for (int s = 0; s < 2; s++) {
      bf16x8 af[FM];
#pragma unroll
      for (int mi = 0; mi < FM; mi++) {
        const int p = wr * (BM / WR) + mi * 16 + (lane & 15);
        const int ch = (s * 4 + (lane >> 4)) ^ (p & 7);
        af[mi] = *(const bf16x8*)(sm + p * 64 + ch * 8);
      }
#pragma unroll
      for (int ni = 0; ni < FN; ni++) {
        const int q = wc * (BN / WC) + ni * 16 + (lane & 15);
        const int ch = (s * 4 + (lane >> 4)) ^ (q & 7);
        bf16x8 bfv = *(const bf16x8*)(sm + BM * 64 + q * 64 + ch * 8);
#pragma unroll
        for (int mi = 0; mi < FM; mi++)
          acc[mi][ni] = __builtin_amdgcn_mfma_f32_16x16x32_bf16(
              af[mi], bfv, acc[mi][ni], 0, 0, 0);
      }
    }
    __syncthreads();
  }

  // epilogue: C/D layout col=lane&15, row=(lane>>4)*4+r
  const int colb = n0 + wc * (BN / WC) + (lane & 15);
  const int rowb = m0 + wr * (BM / WR) + ((lane >> 4) << 2);
#pragma unroll
  for (int ni = 0; ni < FN; ni++) {
    const float bv = bias[colb + ni * 16];
#pragma unroll
    for (int mi = 0; mi < FM; mi++) {
#pragma unroll
      for (int r = 0; r < 4; r++) {
        float v = acc[mi][ni][r] + bv;
        if (RELU) v = fmaxf(v, 0.0f);
        const size_t off = (size_t)(rowb + mi * 16 + r) * N + colb + ni * 16;
        if (WF32) Cf[off] = v;
        if (WB16) {
          bf16 t = __float2bfloat16(v);
          Cb[off] = *(ushort*)&t;
        }
      }
    }
  }
}

// ---------------------------------------------------------------------------
// f32 -> bf16 convert, 8 elems/thread, grid-stride
// ---------------------------------------------------------------------------
__global__ void cvt_bf16_kernel(const float* __restrict__ src,
                                ushort* __restrict__ dst, long n8) {
  long i = (long)blockIdx.x * blockDim.x + threadIdx.x;
  const long stride = (long)gridDim.x * blockDim.x;
  for (; i < n8; i += stride) {
    float4 v0 = ((const float4*)src)[i * 2];
    float4 v1 = ((const float4*)src)[i * 2 + 1];
    float a[8] = {v0.x, v0.y, v0.z, v0.w, v1.x, v1.y, v1.z, v1.w};
    uint h[8];
#pragma unroll
    for (int c = 0; c < 8; c++) {
      bf16 b = __float2bfloat16(a[c]);
      h[c] = *(ushort*)&b;
    }
    uint4 o;
    o.x = h[0] | (h[1] << 16);
    o.y = h[2] | (h[3] << 16);
    o.z = h[4] | (h[5] << 16);
    o.w = h[6] | (h[7] << 16);
    ((uint4*)dst)[i] = o;
  }
}

// ---------------------------------------------------------------------------
// Transposing convert: src (R x C f32) -> dst (C x R bf16)
// ---------------------------------------------------------------------------
__global__ __launch_bounds__(256) void tconv_kernel(
    const float* __restrict__ src, ushort* __restrict__ dst, int R, int C) {
  __shared__ float t[32][33];
  const int c0 = blockIdx.x * 32, r0 = blockIdx.y * 32;
  const int tx = threadIdx.x & 31, ty = threadIdx.x >> 5;
#pragma unroll
  for (int i = 0; i < 32; i += 8)
    t[ty + i][tx] = src[(size_t)(r0 + ty + i) * C + c0 + tx];
  __syncthreads();
#pragma unroll
  for (int i = 0; i < 32; i += 8) {
    bf16 b = __float2bfloat16(t[tx][ty + i]);
    dst[(size_t)(c0 + ty + i) * R + r0 + tx] = *(ushort*)&b;
  }
}

// ---------------------------------------------------------------------------
// Row squared-norm (rows of width 64)
// ---------------------------------------------------------------------------
__global__ void rownorm64_kernel(const float* __restrict__ v,
                                 float* __restrict__ out, int rows) {
  int r = blockIdx.x * blockDim.x + threadIdx.x;
  if (r >= rows) return;
  const float* p = v + (size_t)r * 64;
  float s = 0.0f;
#pragma unroll 8
  for (int k = 0; k < 64; k++) {
    float q = __fmul_rn(p[k], p[k]);
    s = __fadd_rn(s, q);
  }
  out[r] = s;
}

// ---------------------------------------------------------------------------
// VQ argmin via MFMA. d'_j = cn[j] - 2 * <z[r], c[j]>  (zn dropped: row-const)
// Grid: (row_blocks, code_chunks). Block = 4 waves; wave = 16 rows x chunk.
// ---------------------------------------------------------------------------
#define AM_CHUNK 2048
__global__ __launch_bounds__(256) void vq_argmin_mfma(
    const ushort* __restrict__ z16, const ushort* __restrict__ cb16,
    const float* __restrict__ cn, float2* __restrict__ partials) {
  const int tid = threadIdx.x;
  const int lane = tid & 63;
  const int w = tid >> 6;
  const int r0 = blockIdx.x * 64 + w * 16;
  const int c0 = blockIdx.y * AM_CHUNK;

  const ushort* zrow =
      z16 + (size_t)(r0 + (lane & 15)) * 64 + ((lane >> 4) * 8);
  const bf16x8 a0 = *(const bf16x8*)zrow;
  const bf16x8 a1 = *(const bf16x8*)(zrow + 32);

  float best[4];
  int bidx[4];
#pragma unroll
  for (int r = 0; r < 4; r++) {
    best[r] = 3.402823466e38f;
    bidx[r] = 0;
  }

  for (int t = 0; t < AM_CHUNK / 16; t++) {
    const int j = c0 + t * 16 + (lane & 15);
    const ushort* crow = cb16 + (size_t)j * 64 + ((lane >> 4) * 8);
    const bf16x8 b0 = *(const bf16x8*)crow;
    const bf16x8 b1 = *(const bf16x8*)(crow + 32);
    f32x4 acc = {0.0f, 0.0f, 0.0f, 0.0f};
    acc = __builtin_amdgcn_mfma_f32_16x16x32_bf16(a0, b0, acc, 0, 0, 0);
    acc = __builtin_amdgcn_mfma_f32_16x16x32_bf16(a1, b1, acc, 0, 0, 0);
    const float cnv = cn[j];
#pragma unroll
    for (int r = 0; r < 4; r++) {
      const float d = fmaf(-2.0f, acc[r], cnv);
      if (d < best[r]) {  // strict: per-lane j ascends -> first occurrence
        best[r] = d;
        bidx[r] = j;
      }
    }
  }

  // reduce across the 16 code-lanes sharing the same row group
#pragma unroll
  for (int m = 1; m < 16; m <<= 1) {
#pragma unroll
    for (int r = 0; r < 4; r++) {
      const float ov = __shfl_xor(best[r], m, 64);
      const int oi = __shfl_xor(bidx[r], m, 64);
      if (ov < best[r] || (ov == best[r] && oi < bidx[r])) {
        best[r] = ov;
        bidx[r] = oi;
      }
    }
  }
  if ((lane & 15) == 0) {
#pragma unroll
    for (int r = 0; r < 4; r++) {
      const int row = r0 + ((lane >> 4) << 2) + r;
      partials[(size_t)row * (NC / AM_CHUNK) + blockIdx.y] =
          make_float2(best[r], __int_as_float(bidx[r]));
    }
  }
}

__global__ void argmin_reduce_kernel(const float2* __restrict__ partials,
                                     int* __restrict__ idx) {
  const int row = blockIdx.x * 256 + threadIdx.x;
  float2 best = partials[(size_t)row * (NC / AM_CHUNK)];
#pragma unroll
  for (int c = 1; c < NC / AM_CHUNK; c++) {
    const float2 p = partials[(size_t)row * (NC / AM_CHUNK) + c];
    if (p.x < best.x) best = p;  // ties keep earlier chunk (lower codes)
  }
  idx[row] = __float_as_int(best.y);
}

// ---------------------------------------------------------------------------
// z output: out0[r] = z_e[r] + (codebook[idx[r]] - z_e[r]) in f32
// ---------------------------------------------------------------------------
__global__ void gather_z_kernel(const float* __restrict__ z_e,
                                const float* __restrict__ cb,
                                const int* __restrict__ idx,
                                float* __restrict__ out0) {
  int t = blockIdx.x * 256 + threadIdx.x;
  int row = t >> 4;
  int c4 = t & 15;
  int code = idx[row];
  float4 q = *reinterpret_cast<const float4*>(&cb[(size_t)code * 64 + c4 * 4]);
  float4 e = *reinterpret_cast<const float4*>(&z_e[(size_t)row * 64 + c4 * 4]);
  float4 o;
  o.x = __fadd_rn(e.x, __fsub_rn(q.x, e.x));
  o.y = __fadd_rn(e.y, __fsub_rn(q.y, e.y));
  o.z = __fadd_rn(e.z, __fsub_rn(q.z, e.z));
  o.w = __fadd_rn(e.w, __fsub_rn(q.w, e.w));
  *reinterpret_cast<float4*>(&out0[(size_t)row * 64 + c4 * 4]) = o;
}

__global__ void gather_recon_kernel(const float* __restrict__ table,
                                    const int* __restrict__ idx,
                                    float* __restrict__ out1) {
  int row = blockIdx.x >> 2;
  int q = blockIdx.x & 3;
  int c4 = q * 256 + threadIdx.x;
  int code = idx[row];
  float4 v = *reinterpret_cast<const float4*>(
      &table[(size_t)code * 4096 + (size_t)c4 * 4]);
  *reinterpret_cast<float4*>(&out1[(size_t)row * 4096 + (size_t)c4 * 4]) = v;
}

// ---------------------------------------------------------------------------
extern "C" void kernel_launch(void* const* d_in, const int* in_sizes, int n_in,
                              void* d_out, int out_size, void* d_ws,
                              size_t ws_size, hipStream_t stream) {
  const float* x   = (const float*)d_in[0];
  const float* W1  = (const float*)d_in[1];
  const float* b1  = (const float*)d_in[2];
  const float* W2  = (const float*)d_in[3];
  const float* b2  = (const float*)d_in[4];
  const float* cb  = (const float*)d_in[5];
  const float* dW1 = (const float*)d_in[6];
  const float* db1 = (const float*)d_in[7];
  const float* dW2 = (const float*)d_in[8];
  const float* db2 = (const float*)d_in[9];

  float* out0 = (float*)d_out;                      // z: 16384 x 64 (4 MB)
  char* o1b = (char*)d_out + (size_t)BROWS * BOT * 4;  // x_recon region 256 MB
  float* out1 = (float*)o1b;

  // out1-region scratch (all dead before gather_recon overwrites out1):
  ushort* x16   = (ushort*)(o1b);                    // [0,128M)   a..GEMM1
  ushort* W1t   = (ushort*)(o1b + 128 * MB);         // [128,144M) ..GEMM1
  ushort* h16   = (ushort*)(o1b + 144 * MB);         // [144,208M) GEMM1..GEMM2
  float*  z_e   = (float*)(o1b + 64 * MB);           // [64,68M)   GEMM2..gather
  ushort* z16   = (ushort*)(o1b + 68 * MB);          // [68,70M)   GEMM2..argmin
  ushort* cb16  = (ushort*)(o1b + 70 * MB);          // [70,71M)   ..dec-hidden
  float*  cn    = (float*)(o1b + 71 * MB);           // 32 KB      ..argmin
  float2* parts = (float2*)(o1b + 71 * MB + 524288); // 512 KB     argmin..red
  ushort* W2t   = (ushort*)(o1b + 72 * MB);          // 256 KB     ..GEMM2
  ushort* dW1t  = (ushort*)(o1b + 73 * MB);          // 256 KB     ..dec-hidden
  ushort* ht16  = (ushort*)(o1b);                    // [0,32M)    dec..table
  ushort* dW2t  = (ushort*)(o1b + 32 * MB);          // [32,64M)   ..table

  // workspace: table + idx only (high-water ~128.1 MB, < proven 138.5)
  char* wsb = (char*)d_ws;
  float* table = (float*)wsb;                        // [0,128M)   table..gather
  int*   idxb  = (int*)(wsb + 128 * MB);             // 64 KB      red..gathers

  dim3 blk(256);

  // a. x -> bf16
  cvt_bf16_kernel<<<dim3(2048), blk, 0, stream>>>(x, x16,
                                                  (long)BROWS * INDIM / 8);
  // b. W1^T -> bf16 (2048 x 4096)
  tconv_kernel<<<dim3(HID / 32, INDIM / 32), blk, 0, stream>>>(W1, W1t, INDIM,
                                                               HID);
  // c. GEMM1: h = relu(x @ W1 + b1), bf16 out   M=16384 N=2048 K=4096
  gemm_bt<128, 128, 2, 2, true, false, true>
      <<<dim3(HID / 128, BROWS / 128), blk, 0, stream>>>(
          x16, W1t, b1, nullptr, h16, BROWS, HID, INDIM);
  // d. W2^T -> bf16 (64 x 2048)
  tconv_kernel<<<dim3(BOT / 32, HID / 32), blk, 0, stream>>>(W2, W2t, HID,
                                                             BOT);
  // e. GEMM2: z_e = h @ W2 + b2, f32 + bf16 out  M=16384 N=64 K=2048
  gemm_bt<64, 64, 2, 2, false, true, true>
      <<<dim3(1, BROWS / 64), blk, 0, stream>>>(h16, W2t, b2, z_e, z16, BROWS,
                                                BOT, HID);
  // f. codebook -> bf16
  cvt_bf16_kernel<<<dim3(256), blk, 0, stream>>>(cb, cb16, (long)NC * BOT / 8);
  // g. cn = ||c||^2
  rownorm64_kernel<<<dim3(NC / 256), blk, 0, stream>>>(cb, cn, NC);
  // h. argmin (MFMA, 4 code chunks)
  vq_argmin_mfma<<<dim3(BROWS / 64, NC / AM_CHUNK), blk, 0, stream>>>(
      z16, cb16, cn, parts);
  // i. reduce chunks
  argmin_reduce_kernel<<<dim3(BROWS / 256), blk, 0, stream>>>(parts, idxb);
  // j. dW1^T -> bf16 (2048 x 64)
  tconv_kernel<<<dim3(HID / 32, BOT / 32), blk, 0, stream>>>(dW1, dW1t, BOT,
                                                             HID);
  // k. decoder hidden: ht = relu(cb @ dW1 + db1), bf16 out M=8192 N=2048 K=64
  gemm_bt<128, 128, 2, 2, true, false, true>
      <<<dim3(HID / 128, NC / 128), blk, 0, stream>>>(cb16, dW1t, db1, nullptr,
                                                      ht16, NC, HID, BOT);
  // l. dW2^T -> bf16 (4096 x 2048)
  tconv_kernel<<<dim3(INDIM / 32, HID / 32), blk, 0, stream>>>(dW2, dW2t, HID,
                                                               INDIM);
  // m. table = ht @ dW2 + db2, f32 out  M=8192 N=4096 K=2048
  gemm_bt<128, 128, 2, 2, false, true, false>
      <<<dim3(INDIM / 128, NC / 128), blk, 0, stream>>>(
          ht16, dW2t, db2, table, nullptr, NC, INDIM, HID);
  // n. z output
  gather_z_kernel<<<dim3(BROWS * 16 / 256), blk, 0, stream>>>(z_e, cb, idxb,
                                                              out0);
  // o. x_recon output
  gather_recon_kernel<<<dim3(BROWS * 4), blk, 0, stream>>>(table, idxb, out1);
}

// Round 5
// 732.250 us; speedup vs baseline: 7.2949x; 1.0490x over previous
//
#include <hip/hip_runtime.h>
#include <hip/hip_bf16.h>

// Problem constants
#define BROWS 16384
#define INDIM 4096
#define HID   2048
#define BOT   64
#define NC    8192

typedef __hip_bfloat16 bf16;
typedef __attribute__((ext_vector_type(8))) short bf16x8;
typedef __attribute__((ext_vector_type(4))) float f32x4;

#define MB (1048576L)

// ===========================================================================
// 256x256-tile 8-wave 4-phase/K-tile bf16 MFMA GEMM (T1+T2+T3+T4+T5).
// C = [relu](A @ B^T + bias). A: M x K row-major bf16; B: N x K row-major
// (transposed operand). BK=64. 512 threads = 8 waves (2M x 4N); per-wave
// output 128x64 = 8x4 fragments of 16x16. LDS = 2 buffers x (A 32KB + B
// 32KB) = 128 KB. XOR chunk swizzle (16B chunk ^ row&7), proven 0-conflict.
// Staging: B(t+1) issued at phase 0, A(t+2) at phase 3; boundary vmcnt(4).
// ===========================================================================
__device__ __forceinline__ void lda8(const short* base, int wr, int hi, int lo,
                                     int s, bf16x8 (&a)[8]) {
#pragma unroll
  for (int mi = 0; mi < 8; mi++) {
    const int p = wr * 128 + mi * 16 + lo;
    const int ch = (s * 4 + hi) ^ (p & 7);
    a[mi] = *(const bf16x8*)(base + p * 64 + ch * 8);
  }
}

__device__ __forceinline__ void ldb2(const short* base, int wc, int hi, int lo,
                                     int s, int nh, bf16x8 (&b)[2]) {
#pragma unroll
  for (int kk = 0; kk < 2; kk++) {
    const int q = wc * 64 + (nh * 2 + kk) * 16 + lo;
    const int ch = (s * 4 + hi) ^ (q & 7);
    b[kk] = *(const bf16x8*)(base + q * 64 + ch * 8);
  }
}

template <int NH>
__device__ __forceinline__ void mm_quad(f32x4 (&acc)[8][4],
                                        const bf16x8 (&a)[8],
                                        const bf16x8 (&bq)[2]) {
#pragma unroll
  for (int kk = 0; kk < 2; kk++)
#pragma unroll
    for (int mi = 0; mi < 8; mi++)
      acc[mi][NH * 2 + kk] = __builtin_amdgcn_mfma_f32_16x16x32_bf16(
          a[mi], bq[kk], acc[mi][NH * 2 + kk], 0, 0, 0);
}

template <bool RELU, bool WF32, bool WB16>
__global__ __launch_bounds__(512, 2) void gemm256(
    const ushort* __restrict__ A, const ushort* __restrict__ B,
    const float* __restrict__ bias, float* __restrict__ Cf,
    ushort* __restrict__ Cb, int M, int N, int K) {
  __shared__ __align__(16) short sm[65536];  // 128 KB

  const int tid = threadIdx.x;
  const int lane = tid & 63;
  const int w = tid >> 6;             // 0..7
  const int wr = w >> 2, wc = w & 3;  // 2 x 4 wave grid
  const int hi = lane >> 4, lo = lane & 15;

  // XCD-aware bijective swizzle (grids here are %8==0)
  const int nwg = gridDim.x * gridDim.y;
  int bid = blockIdx.y * gridDim.x + blockIdx.x;
  if ((nwg & 7) == 0) bid = (bid & 7) * (nwg >> 3) + (bid >> 3);
  const int bx = bid % gridDim.x, by = bid / gridDim.x;
  const int m0 = by * 256, n0 = bx * 256;

  const ushort* Ag = A + (size_t)m0 * K;
  const ushort* Bg = B + (size_t)n0 * K;

  f32x4 acc[8][4] = {};

  // stage one 256x64 bf16 tile (32KB) at K-offset kelem into LDS short-offset
  // dstShort. 4 x global_load_lds_dwordx4 per thread; linear dest, inverse-
  // swizzled source (chunk kc = (c&7) ^ (r&7)).
  auto STAGE = [&](const ushort* G, int kelem, int dstShort) {
#pragma unroll
    for (int i = 0; i < 4; i++) {
      const int cc = i * 512 + tid;   // 16B-chunk index 0..2047
      const int r = cc >> 3;          // row 0..255
      const int kc = (cc & 7) ^ (r & 7);
      const ushort* src = G + (size_t)r * K + kelem + kc * 8;
      uint32_t m0v = __builtin_amdgcn_readfirstlane(
          (uint32_t)(uintptr_t)(sm + dstShort + (i * 512 + w * 64) * 8));
      asm volatile("s_mov_b32 m0, %0\n\t"
                   "global_load_lds_dwordx4 %1, off\n\t"
                   :: "s"(m0v), "v"(src) : "memory");
    }
  };

  const int nt = K / 64;  // >= 32 for all call sites

  // prologue: A(0),B(0) -> buf0; A(1) -> buf1; wait A(0),B(0) (allow A(1))
  STAGE(Ag, 0, 0);
  STAGE(Bg, 0, 16384);
  STAGE(Ag, 64, 32768);
  asm volatile("s_waitcnt vmcnt(4)" ::: "memory");
  __builtin_amdgcn_s_barrier();

  for (int t = 0; t < nt; t++) {
    const int c = t & 1;
    const int aB = c * 32768, bB = aB + 16384;
    bf16x8 a[8], bq[2];

    // ---- phase 0: kstep 0, B-frags 0-1; issue stage B(t+1) -> buf[c^1] ----
    lda8(sm + aB, wr, hi, lo, 0, a);
    ldb2(sm + bB, wc, hi, lo, 0, 0, bq);
    if (t + 1 < nt) STAGE(Bg, (t + 1) * 64, (((t + 1) & 1) * 32768) + 16384);
    __builtin_amdgcn_s_barrier();
    asm volatile("s_waitcnt lgkmcnt(0)" ::: "memory");
    __builtin_amdgcn_sched_barrier(0);
    __builtin_amdgcn_s_setprio(1);
    mm_quad<0>(acc, a, bq);
    __builtin_amdgcn_s_setprio(0);
    __builtin_amdgcn_s_barrier();

    // ---- phase 1: kstep 0, B-frags 2-3 (A reused in reg) ----
    ldb2(sm + bB, wc, hi, lo, 0, 1, bq);
    __builtin_amdgcn_s_barrier();
    asm volatile("s_waitcnt lgkmcnt(0)" ::: "memory");
    __builtin_amdgcn_sched_barrier(0);
    __builtin_amdgcn_s_setprio(1);
    mm_quad<1>(acc, a, bq);
    __builtin_amdgcn_s_setprio(0);
    __builtin_amdgcn_s_barrier();

    // ---- phase 2: kstep 1, B-frags 0-1 ----
    lda8(sm + aB, wr, hi, lo, 1, a);
    ldb2(sm + bB, wc, hi, lo, 1, 0, bq);
    __builtin_amdgcn_s_barrier();
    asm volatile("s_waitcnt lgkmcnt(0)" ::: "memory");
    __builtin_amdgcn_sched_barrier(0);
    __builtin_amdgcn_s_setprio(1);
    mm_quad<0>(acc, a, bq);
    __builtin_amdgcn_s_setprio(0);
    __builtin_amdgcn_s_barrier();

    // ---- phase 3: kstep 1, B-frags 2-3; stage A(t+2) -> buf[c] A-region
    //      (A[c] fully consumed after phase 2's barrier); boundary vmcnt ----
    ldb2(sm + bB, wc, hi, lo, 1, 1, bq);
    if (t + 2 < nt) STAGE(Ag, (t + 2) * 64, c * 32768);
    __builtin_amdgcn_s_barrier();
    asm volatile("s_waitcnt lgkmcnt(0)" ::: "memory");
    __builtin_amdgcn_sched_barrier(0);
    __builtin_amdgcn_s_setprio(1);
    mm_quad<1>(acc, a, bq);
    __builtin_amdgcn_s_setprio(0);
    // need B(t+1) landed; allow A(t+2) (4 loads) to stay in flight
    if (t + 2 < nt)
      asm volatile("s_waitcnt vmcnt(4)" ::: "memory");
    else if (t + 1 < nt)
      asm volatile("s_waitcnt vmcnt(0)" ::: "memory");
    __builtin_amdgcn_s_barrier();
  }

  // epilogue: C/D layout col=lane&15, row=(lane>>4)*4+r
  const int colb = n0 + wc * 64 + lo;
  const int rowb = m0 + wr * 128 + hi * 4;
#pragma unroll
  for (int ni = 0; ni < 4; ni++) {
    const float bv = bias[colb + ni * 16];
#pragma unroll
    for (int mi = 0; mi < 8; mi++) {
#pragma unroll
      for (int r = 0; r < 4; r++) {
        float v = acc[mi][ni][r] + bv;
        if (RELU) v = fmaxf(v, 0.0f);
        const size_t off = (size_t)(rowb + mi * 16 + r) * N + colb + ni * 16;
        if (WF32) Cf[off] = v;
        if (WB16) {
          bf16 tb = __float2bfloat16(v);
          Cb[off] = *(ushort*)&tb;
        }
      }
    }
  }
}

// ---------------------------------------------------------------------------
// 128²/64² bf16 MFMA GEMM (round-3 proven) — kept for GEMM2 (N=64) and the
// decoder hidden layer (K=64), where the 256² tile doesn't fit.
// ---------------------------------------------------------------------------
template <int BM, int BN, int WR, int WC, bool RELU, bool WF32, bool WB16>
__global__ __launch_bounds__(256, 3) void gemm_bt(
    const ushort* __restrict__ A, const ushort* __restrict__ B,
    const float* __restrict__ bias, float* __restrict__ Cf,
    ushort* __restrict__ Cb, int M, int N, int K) {
  constexpr int FM = (BM / WR) / 16;
  constexpr int FN = (BN / WC) / 16;
  __shared__ __align__(16) short sm[(BM + BN) * 64];

  const int tid = threadIdx.x;
  const int lane = tid & 63;
  const int w = tid >> 6;
  const int wr = w / WC, wc = w % WC;

  const int nwg = gridDim.x * gridDim.y;
  int bid = blockIdx.y * gridDim.x + blockIdx.x;
  if ((nwg & 7) == 0) bid = (bid & 7) * (nwg >> 3) + (bid >> 3);
  const int bx = bid % gridDim.x, by = bid / gridDim.x;
  const int m0 = by * BM, n0 = bx * BN;

  const ushort* Ag = A + (size_t)m0 * K;
  const ushort* Bg = B + (size_t)n0 * K;

  f32x4 acc[FM][FN] = {};

  for (int kt = 0; kt < K; kt += 64) {
#pragma unroll
    for (int j = 0; j < BM / 32; j++) {
      const int cb = j * 256 + w * 64;
      const int c = cb + lane;
      const int r = c >> 3;
      const int kc = (c & 7) ^ (r & 7);
      const ushort* src = Ag + (size_t)r * K + kt + kc * 8;
      const short* ld = sm + cb * 8;
      uint32_t m0v = __builtin_amdgcn_readfirstlane((uint32_t)(uintptr_t)ld);
      asm volatile("s_mov_b32 m0, %0\n\t"
                   "global_load_lds_dwordx4 %1, off\n\t"
                   :: "s"(m0v), "v"(src) : "memory");
    }
#pragma unroll
    for (int j = 0; j < BN / 32; j++) {
      const int cb = j * 256 + w * 64;
      const int c = cb + lane;
      const int r = c >> 3;
      const int kc = (c & 7) ^ (r & 7);
      const ushort* src = Bg + (size_t)r * K + kt + kc * 8;
      const short* ld = sm + (BM * 8 + cb) * 8;
      uint32_t m0v = __builtin_amdgcn_readfirstlane((uint32_t)(uintptr_t)ld);
      asm volatile("s_mov_b32 m0, %0\n\t"
                   "global_load_lds_dwordx4 %1, off\n\t"
                   :: "s"(m0v), "v"(src) : "memory");
    }
    asm volatile("s_waitcnt vmcnt(0)" ::: "memory");
    __syncthreads();

#pragma unroll
    for (int s = 0; s < 2; s++) {
      bf16x8 af[FM];
#pragma unroll
      for (int mi = 0; mi < FM; mi++) {
        const int p = wr * (BM / WR) + mi * 16 + (lane & 15);
        const int ch = (s * 4 + (lane >> 4)) ^ (p & 7);
        af[mi] = *(const bf16x8*)(sm + p * 64 + ch * 8);
      }
#pragma unroll
      for (int ni = 0; ni < FN; ni++) {
        const int q = wc * (BN / WC) + ni * 16 + (lane & 15);
        const int ch = (s * 4 + (lane >> 4)) ^ (q & 7);
        bf16x8 bfv = *(const bf16x8*)(sm + BM * 64 + q * 64 + ch * 8);
#pragma unroll
        for (int mi = 0; mi < FM; mi++)
          acc[mi][ni] = __builtin_amdgcn_mfma_f32_16x16x32_bf16(
              af[mi], bfv, acc[mi][ni], 0, 0, 0);
      }
    }
    __syncthreads();
  }

  const int colb = n0 + wc * (BN / WC) + (lane & 15);
  const int rowb = m0 + wr * (BM / WR) + ((lane >> 4) << 2);
#pragma unroll
  for (int ni = 0; ni < FN; ni++) {
    const float bv = bias[colb + ni * 16];
#pragma unroll
    for (int mi = 0; mi < FM; mi++) {
#pragma unroll
      for (int r = 0; r < 4; r++) {
        float v = acc[mi][ni][r] + bv;
        if (RELU) v = fmaxf(v, 0.0f);
        const size_t off = (size_t)(rowb + mi * 16 + r) * N + colb + ni * 16;
        if (WF32) Cf[off] = v;
        if (WB16) {
          bf16 t = __float2bfloat16(v);
          Cb[off] = *(ushort*)&t;
        }
      }
    }
  }
}

// ---------------------------------------------------------------------------
// f32 -> bf16 convert, 8 elems/thread, grid-stride
// ---------------------------------------------------------------------------
__global__ void cvt_bf16_kernel(const float* __restrict__ src,
                                ushort* __restrict__ dst, long n8) {
  long i = (long)blockIdx.x * blockDim.x + threadIdx.x;
  const long stride = (long)gridDim.x * blockDim.x;
  for (; i < n8; i += stride) {
    float4 v0 = ((const float4*)src)[i * 2];
    float4 v1 = ((const float4*)src)[i * 2 + 1];
    float a[8] = {v0.x, v0.y, v0.z, v0.w, v1.x, v1.y, v1.z, v1.w};
    uint h[8];
#pragma unroll
    for (int c = 0; c < 8; c++) {
      bf16 b = __float2bfloat16(a[c]);
      h[c] = *(ushort*)&b;
    }
    uint4 o;
    o.x = h[0] | (h[1] << 16);
    o.y = h[2] | (h[3] << 16);
    o.z = h[4] | (h[5] << 16);
    o.w = h[6] | (h[7] << 16);
    ((uint4*)dst)[i] = o;
  }
}

// ---------------------------------------------------------------------------
// Transposing convert: src (R x C f32) -> dst (C x R bf16)
// ---------------------------------------------------------------------------
__global__ __launch_bounds__(256) void tconv_kernel(
    const float* __restrict__ src, ushort* __restrict__ dst, int R, int C) {
  __shared__ float t[32][33];
  const int c0 = blockIdx.x * 32, r0 = blockIdx.y * 32;
  const int tx = threadIdx.x & 31, ty = threadIdx.x >> 5;
#pragma unroll
  for (int i = 0; i < 32; i += 8)
    t[ty + i][tx] = src[(size_t)(r0 + ty + i) * C + c0 + tx];
  __syncthreads();
#pragma unroll
  for (int i = 0; i < 32; i += 8) {
    bf16 b = __float2bfloat16(t[tx][ty + i]);
    dst[(size_t)(c0 + ty + i) * R + r0 + tx] = *(ushort*)&b;
  }
}

// ---------------------------------------------------------------------------
// Row squared-norm (rows of width 64)
// ---------------------------------------------------------------------------
__global__ void rownorm64_kernel(const float* __restrict__ v,
                                 float* __restrict__ out, int rows) {
  int r = blockIdx.x * blockDim.x + threadIdx.x;
  if (r >= rows) return;
  const float* p = v + (size_t)r * 64;
  float s = 0.0f;
#pragma unroll 8
  for (int k = 0; k < 64; k++) {
    float q = __fmul_rn(p[k], p[k]);
    s = __fadd_rn(s, q);
  }
  out[r] = s;
}

// ---------------------------------------------------------------------------
// VQ argmin via MFMA. d'_j = cn[j] - 2 * <z[r], c[j]>  (zn dropped: row-const)
// ---------------------------------------------------------------------------
#define AM_CHUNK 2048
__global__ __launch_bounds__(256) void vq_argmin_mfma(
    const ushort* __restrict__ z16, const ushort* __restrict__ cb16,
    const float* __restrict__ cn, float2* __restrict__ partials) {
  const int tid = threadIdx.x;
  const int lane = tid & 63;
  const int w = tid >> 6;
  const int r0 = blockIdx.x * 64 + w * 16;
  const int c0 = blockIdx.y * AM_CHUNK;

  const ushort* zrow =
      z16 + (size_t)(r0 + (lane & 15)) * 64 + ((lane >> 4) * 8);
  const bf16x8 a0 = *(const bf16x8*)zrow;
  const bf16x8 a1 = *(const bf16x8*)(zrow + 32);

  float best[4];
  int bidx[4];
#pragma unroll
  for (int r = 0; r < 4; r++) {
    best[r] = 3.402823466e38f;
    bidx[r] = 0;
  }

  for (int t = 0; t < AM_CHUNK / 16; t++) {
    const int j = c0 + t * 16 + (lane & 15);
    const ushort* crow = cb16 + (size_t)j * 64 + ((lane >> 4) * 8);
    const bf16x8 b0 = *(const bf16x8*)crow;
    const bf16x8 b1 = *(const bf16x8*)(crow + 32);
    f32x4 acc = {0.0f, 0.0f, 0.0f, 0.0f};
    acc = __builtin_amdgcn_mfma_f32_16x16x32_bf16(a0, b0, acc, 0, 0, 0);
    acc = __builtin_amdgcn_mfma_f32_16x16x32_bf16(a1, b1, acc, 0, 0, 0);
    const float cnv = cn[j];
#pragma unroll
    for (int r = 0; r < 4; r++) {
      const float d = fmaf(-2.0f, acc[r], cnv);
      if (d < best[r]) {
        best[r] = d;
        bidx[r] = j;
      }
    }
  }

#pragma unroll
  for (int m = 1; m < 16; m <<= 1) {
#pragma unroll
    for (int r = 0; r < 4; r++) {
      const float ov = __shfl_xor(best[r], m, 64);
      const int oi = __shfl_xor(bidx[r], m, 64);
      if (ov < best[r] || (ov == best[r] && oi < bidx[r])) {
        best[r] = ov;
        bidx[r] = oi;
      }
    }
  }
  if ((lane & 15) == 0) {
#pragma unroll
    for (int r = 0; r < 4; r++) {
      const int row = r0 + ((lane >> 4) << 2) + r;
      partials[(size_t)row * (NC / AM_CHUNK) + blockIdx.y] =
          make_float2(best[r], __int_as_float(bidx[r]));
    }
  }
}

__global__ void argmin_reduce_kernel(const float2* __restrict__ partials,
                                     int* __restrict__ idx) {
  const int row = blockIdx.x * 256 + threadIdx.x;
  float2 best = partials[(size_t)row * (NC / AM_CHUNK)];
#pragma unroll
  for (int c = 1; c < NC / AM_CHUNK; c++) {
    const float2 p = partials[(size_t)row * (NC / AM_CHUNK) + c];
    if (p.x < best.x) best = p;
  }
  idx[row] = __float_as_int(best.y);
}

// ---------------------------------------------------------------------------
// z output: out0[r] = z_e[r] + (codebook[idx[r]] - z_e[r]) in f32
// ---------------------------------------------------------------------------
__global__ void gather_z_kernel(const float* __restrict__ z_e,
                                const float* __restrict__ cb,
                                const int* __restrict__ idx,
                                float* __restrict__ out0) {
  int t = blockIdx.x * 256 + threadIdx.x;
  int row = t >> 4;
  int c4 = t & 15;
  int code = idx[row];
  float4 q = *reinterpret_cast<const float4*>(&cb[(size_t)code * 64 + c4 * 4]);
  float4 e = *reinterpret_cast<const float4*>(&z_e[(size_t)row * 64 + c4 * 4]);
  float4 o;
  o.x = __fadd_rn(e.x, __fsub_rn(q.x, e.x));
  o.y = __fadd_rn(e.y, __fsub_rn(q.y, e.y));
  o.z = __fadd_rn(e.z, __fsub_rn(q.z, e.z));
  o.w = __fadd_rn(e.w, __fsub_rn(q.w, e.w));
  *reinterpret_cast<float4*>(&out0[(size_t)row * 64 + c4 * 4]) = o;
}

__global__ void gather_recon_kernel(const float* __restrict__ table,
                                    const int* __restrict__ idx,
                                    float* __restrict__ out1) {
  int row = blockIdx.x >> 2;
  int q = blockIdx.x & 3;
  int c4 = q * 256 + threadIdx.x;
  int code = idx[row];
  float4 v = *reinterpret_cast<const float4*>(
      &table[(size_t)code * 4096 + (size_t)c4 * 4]);
  *reinterpret_cast<float4*>(&out1[(size_t)row * 4096 + (size_t)c4 * 4]) = v;
}

// ---------------------------------------------------------------------------
extern "C" void kernel_launch(void* const* d_in, const int* in_sizes, int n_in,
                              void* d_out, int out_size, void* d_ws,
                              size_t ws_size, hipStream_t stream) {
  const float* x   = (const float*)d_in[0];
  const float* W1  = (const float*)d_in[1];
  const float* b1  = (const float*)d_in[2];
  const float* W2  = (const float*)d_in[3];
  const float* b2  = (const float*)d_in[4];
  const float* cb  = (const float*)d_in[5];
  const float* dW1 = (const float*)d_in[6];
  const float* db1 = (const float*)d_in[7];
  const float* dW2 = (const float*)d_in[8];
  const float* db2 = (const float*)d_in[9];

  float* out0 = (float*)d_out;                      // z: 16384 x 64 (4 MB)
  char* o1b = (char*)d_out + (size_t)BROWS * BOT * 4;  // x_recon region 256 MB
  float* out1 = (float*)o1b;

  // out1-region scratch (all dead before gather_recon overwrites out1):
  ushort* x16   = (ushort*)(o1b);                    // [0,128M)   a..GEMM1
  ushort* W1t   = (ushort*)(o1b + 128 * MB);         // [128,144M) ..GEMM1
  ushort* h16   = (ushort*)(o1b + 144 * MB);         // [144,208M) GEMM1..GEMM2
  float*  z_e   = (float*)(o1b + 64 * MB);           // [64,68M)   GEMM2..gather
  ushort* z16   = (ushort*)(o1b + 68 * MB);          // [68,70M)   GEMM2..argmin
  ushort* cb16  = (ushort*)(o1b + 70 * MB);          // [70,71M)   ..dec-hidden
  float*  cn    = (float*)(o1b + 71 * MB);           // 32 KB      ..argmin
  float2* parts = (float2*)(o1b + 71 * MB + 524288); // 512 KB     argmin..red
  ushort* W2t   = (ushort*)(o1b + 72 * MB);          // 256 KB     ..GEMM2
  ushort* dW1t  = (ushort*)(o1b + 73 * MB);          // 256 KB     ..dec-hidden
  ushort* ht16  = (ushort*)(o1b);                    // [0,32M)    dec..table
  ushort* dW2t  = (ushort*)(o1b + 32 * MB);          // [32,64M)   ..table

  // workspace: table + idx only (high-water ~128.1 MB)
  char* wsb = (char*)d_ws;
  float* table = (float*)wsb;                        // [0,128M)   table..gather
  int*   idxb  = (int*)(wsb + 128 * MB);             // 64 KB      red..gathers

  dim3 blk(256);

  // a. x -> bf16
  cvt_bf16_kernel<<<dim3(2048), blk, 0, stream>>>(x, x16,
                                                  (long)BROWS * INDIM / 8);
  // b. W1^T -> bf16 (2048 x 4096)
  tconv_kernel<<<dim3(HID / 32, INDIM / 32), blk, 0, stream>>>(W1, W1t, INDIM,
                                                               HID);
  // c. GEMM1: h = relu(x @ W1 + b1), bf16 out   M=16384 N=2048 K=4096
  gemm256<true, false, true>
      <<<dim3(HID / 256, BROWS / 256), dim3(512), 0, stream>>>(
          x16, W1t, b1, nullptr, h16, BROWS, HID, INDIM);
  // d. W2^T -> bf16 (64 x 2048)
  tconv_kernel<<<dim3(BOT / 32, HID / 32), blk, 0, stream>>>(W2, W2t, HID,
                                                             BOT);
  // e. GEMM2: z_e = h @ W2 + b2, f32 + bf16 out  M=16384 N=64 K=2048
  gemm_bt<64, 64, 2, 2, false, true, true>
      <<<dim3(1, BROWS / 64), blk, 0, stream>>>(h16, W2t, b2, z_e, z16, BROWS,
                                                BOT, HID);
  // f. codebook -> bf16
  cvt_bf16_kernel<<<dim3(256), blk, 0, stream>>>(cb, cb16, (long)NC * BOT / 8);
  // g. cn = ||c||^2
  rownorm64_kernel<<<dim3(NC / 256), blk, 0, stream>>>(cb, cn, NC);
  // h. argmin (MFMA, 4 code chunks)
  vq_argmin_mfma<<<dim3(BROWS / 64, NC / AM_CHUNK), blk, 0, stream>>>(
      z16, cb16, cn, parts);
  // i. reduce chunks
  argmin_reduce_kernel<<<dim3(BROWS / 256), blk, 0, stream>>>(parts, idxb);
  // j. dW1^T -> bf16 (2048 x 64)
  tconv_kernel<<<dim3(HID / 32, BOT / 32), blk, 0, stream>>>(dW1, dW1t, BOT,
                                                             HID);
  // k. decoder hidden: ht = relu(cb @ dW1 + db1), bf16 out M=8192 N=2048 K=64
  gemm_bt<128, 128, 2, 2, true, false, true>
      <<<dim3(HID / 128, NC / 128), blk, 0, stream>>>(cb16, dW1t, db1, nullptr,
                                                      ht16, NC, HID, BOT);
  // l. dW2^T -> bf16 (4096 x 2048)
  tconv_kernel<<<dim3(INDIM / 32, HID / 32), blk, 0, stream>>>(dW2, dW2t, HID,
                                                               INDIM);
  // m. table = ht @ dW2 + db2, f32 out  M=8192 N=4096 K=2048
  gemm256<false, true, false>
      <<<dim3(INDIM / 256, NC / 256), dim3(512), 0, stream>>>(
          ht16, dW2t, db2, table, nullptr, NC, INDIM, HID);
  // n. z output
  gather_z_kernel<<<dim3(BROWS * 16 / 256), blk, 0, stream>>>(z_e, cb, idxb,
                                                              out0);
  // o. x_recon output
  gather_recon_kernel<<<dim3(BROWS * 4), blk, 0, stream>>>(table, idxb, out1);
}

// Round 6
// 729.179 us; speedup vs baseline: 7.3257x; 1.0042x over previous
//
#include <hip/hip_runtime.h>
#include <hip/hip_bf16.h>

// Problem constants
#define BROWS 16384
#define INDIM 4096
#define HID   2048
#define BOT   64
#define NC    8192

typedef __hip_bfloat16 bf16;
typedef __attribute__((ext_vector_type(8))) short bf16x8;
typedef __attribute__((ext_vector_type(4))) float f32x4;

#define MB (1048576L)

// ===========================================================================
// 256x256-tile 8-wave bf16 MFMA GEMM, 2 phases/K-tile with register
// read-ahead (v2). C = [relu](A @ B^T + bias). A: M x K row-major bf16;
// B: N x K row-major (transposed operand). BK=64. 512 threads = 8 waves
// (2M x 4N); per-wave output 128x64 = 8x4 fragments of 16x16.
// LDS = 2 buffers x (A 32KB + B 32KB) = 128 KB; XOR chunk swizzle.
// Schedule per K-tile t (consuming buf c=t&1):
//   issue ds_reads a0,b0,a1 (20) -> MFMA s0 (compiler's counted lgkm waits
//   let a1 fly under s0) -> issue b1 -> lgkmcnt(0)+barrier (all waves done
//   reading buf c) -> STAGE A(t+2)+B(t+2) into buf c (8 gloads, ~1.5-tile
//   lead) -> MFMA s1 -> vmcnt(8) (t+1's 8 loads landed; t+2's in flight)
//   -> barrier.
// ===========================================================================
__device__ __forceinline__ void lda8(const short* base, int wr, int hi, int lo,
                                     int s, bf16x8 (&a)[8]) {
#pragma unroll
  for (int mi = 0; mi < 8; mi++) {
    const int p = wr * 128 + mi * 16 + lo;
    const int ch = (s * 4 + hi) ^ (p & 7);
    a[mi] = *(const bf16x8*)(base + p * 64 + ch * 8);
  }
}

__device__ __forceinline__ void ldb4(const short* base, int wc, int hi, int lo,
                                     int s, bf16x8 (&b)[4]) {
#pragma unroll
  for (int ni = 0; ni < 4; ni++) {
    const int q = wc * 64 + ni * 16 + lo;
    const int ch = (s * 4 + hi) ^ (q & 7);
    b[ni] = *(const bf16x8*)(base + q * 64 + ch * 8);
  }
}

template <bool RELU, bool WF32, bool WB16>
__global__ __launch_bounds__(512, 2) void gemm256(
    const ushort* __restrict__ A, const ushort* __restrict__ B,
    const float* __restrict__ bias, float* __restrict__ Cf,
    ushort* __restrict__ Cb, int M, int N, int K) {
  __shared__ __align__(16) short sm[65536];  // 128 KB

  const int tid = threadIdx.x;
  const int lane = tid & 63;
  const int w = tid >> 6;             // 0..7
  const int wr = w >> 2, wc = w & 3;  // 2 x 4 wave grid
  const int hi = lane >> 4, lo = lane & 15;

  // XCD-aware bijective swizzle (grids here are %8==0)
  const int nwg = gridDim.x * gridDim.y;
  int bid = blockIdx.y * gridDim.x + blockIdx.x;
  if ((nwg & 7) == 0) bid = (bid & 7) * (nwg >> 3) + (bid >> 3);
  const int bx = bid % gridDim.x, by = bid / gridDim.x;
  const int m0 = by * 256, n0 = bx * 256;

  const ushort* Ag = A + (size_t)m0 * K;
  const ushort* Bg = B + (size_t)n0 * K;

  f32x4 acc[8][4] = {};

  // stage one 256x64 bf16 tile (32KB) at K-offset kelem into LDS short-offset
  // dstShort. 4 x global_load_lds_dwordx4 per thread; linear dest, inverse-
  // swizzled source (chunk kc = (c&7) ^ (r&7)).
  auto STAGE = [&](const ushort* G, int kelem, int dstShort) {
#pragma unroll
    for (int i = 0; i < 4; i++) {
      const int cc = i * 512 + tid;   // 16B-chunk index 0..2047
      const int r = cc >> 3;          // row 0..255
      const int kc = (cc & 7) ^ (r & 7);
      const ushort* src = G + (size_t)r * K + kelem + kc * 8;
      uint32_t m0v = __builtin_amdgcn_readfirstlane(
          (uint32_t)(uintptr_t)(sm + dstShort + (i * 512 + w * 64) * 8));
      asm volatile("s_mov_b32 m0, %0\n\t"
                   "global_load_lds_dwordx4 %1, off\n\t"
                   :: "s"(m0v), "v"(src) : "memory");
    }
  };

  const int nt = K / 64;  // >= 32 for all call sites

  // prologue: tiles 0 and 1 staged; wait tile 0 (8 loads), allow tile 1.
  STAGE(Ag, 0, 0);
  STAGE(Bg, 0, 16384);
  STAGE(Ag, 64, 32768);
  STAGE(Bg, 64, 32768 + 16384);
  asm volatile("s_waitcnt vmcnt(8)" ::: "memory");
  __builtin_amdgcn_s_barrier();

  for (int t = 0; t < nt; t++) {
    const int c = t & 1;
    const int aB = c * 32768, bB = aB + 16384;
    bf16x8 a0[8], b0[4], a1[8], b1[4];

    // issue reads for both k-steps' A and k-step-0 B (20 ds_read_b128);
    // compiler inserts counted lgkm waits, so MFMA s0 starts while a1 flies.
    lda8(sm + aB, wr, hi, lo, 0, a0);
    ldb4(sm + bB, wc, hi, lo, 0, b0);
    lda8(sm + aB, wr, hi, lo, 1, a1);

    __builtin_amdgcn_s_setprio(1);
#pragma unroll
    for (int ni = 0; ni < 4; ni++)
#pragma unroll
      for (int mi = 0; mi < 8; mi++)
        acc[mi][ni] = __builtin_amdgcn_mfma_f32_16x16x32_bf16(
            a0[mi], b0[ni], acc[mi][ni], 0, 0, 0);
    __builtin_amdgcn_s_setprio(0);

    // k-step-1 B reads (late, to cap VGPR pressure; drain below covers them)
    ldb4(sm + bB, wc, hi, lo, 1, b1);

    // all of this wave's reads of buf[c] done, then cross-wave barrier:
    // after it, every wave has finished reading buf[c] -> safe to restage.
    asm volatile("s_waitcnt lgkmcnt(0)" ::: "memory");
    __builtin_amdgcn_s_barrier();

    // stage tile t+2 into buf[c]: ~1.5 K-tiles of lead over first use.
    if (t + 2 < nt) {
      STAGE(Ag, (t + 2) * 64, aB);
      STAGE(Bg, (t + 2) * 64, bB);
    }

    __builtin_amdgcn_s_setprio(1);
#pragma unroll
    for (int ni = 0; ni < 4; ni++)
#pragma unroll
      for (int mi = 0; mi < 8; mi++)
        acc[mi][ni] = __builtin_amdgcn_mfma_f32_16x16x32_bf16(
            a1[mi], b1[ni], acc[mi][ni], 0, 0, 0);
    __builtin_amdgcn_s_setprio(0);

    // boundary: tile t+1's 8 loads must be landed; tile t+2's may fly.
    if (t + 2 < nt)
      asm volatile("s_waitcnt vmcnt(8)" ::: "memory");
    else if (t + 1 < nt)
      asm volatile("s_waitcnt vmcnt(0)" ::: "memory");
    __builtin_amdgcn_s_barrier();
  }

  // epilogue: C/D layout col=lane&15, row=(lane>>4)*4+r
  const int colb = n0 + wc * 64 + lo;
  const int rowb = m0 + wr * 128 + hi * 4;
#pragma unroll
  for (int ni = 0; ni < 4; ni++) {
    const float bv = bias[colb + ni * 16];
#pragma unroll
    for (int mi = 0; mi < 8; mi++) {
#pragma unroll
      for (int r = 0; r < 4; r++) {
        float v = acc[mi][ni][r] + bv;
        if (RELU) v = fmaxf(v, 0.0f);
        const size_t off = (size_t)(rowb + mi * 16 + r) * N + colb + ni * 16;
        if (WF32) Cf[off] = v;
        if (WB16) {
          bf16 tb = __float2bfloat16(v);
          Cb[off] = *(ushort*)&tb;
        }
      }
    }
  }
}

// ---------------------------------------------------------------------------
// 128²/64² bf16 MFMA GEMM (round-3 proven) — kept for GEMM2 (N=64) and the
// decoder hidden layer (K=64), where the 256² tile doesn't fit.
// ---------------------------------------------------------------------------
template <int BM, int BN, int WR, int WC, bool RELU, bool WF32, bool WB16>
__global__ __launch_bounds__(256, 3) void gemm_bt(
    const ushort* __restrict__ A, const ushort* __restrict__ B,
    const float* __restrict__ bias, float* __restrict__ Cf,
    ushort* __restrict__ Cb, int M, int N, int K) {
  constexpr int FM = (BM / WR) / 16;
  constexpr int FN = (BN / WC) / 16;
  __shared__ __align__(16) short sm[(BM + BN) * 64];

  const int tid = threadIdx.x;
  const int lane = tid & 63;
  const int w = tid >> 6;
  const int wr = w / WC, wc = w % WC;

  const int nwg = gridDim.x * gridDim.y;
  int bid = blockIdx.y * gridDim.x + blockIdx.x;
  if ((nwg & 7) == 0) bid = (bid & 7) * (nwg >> 3) + (bid >> 3);
  const int bx = bid % gridDim.x, by = bid / gridDim.x;
  const int m0 = by * BM, n0 = bx * BN;

  const ushort* Ag = A + (size_t)m0 * K;
  const ushort* Bg = B + (size_t)n0 * K;

  f32x4 acc[FM][FN] = {};

  for (int kt = 0; kt < K; kt += 64) {
#pragma unroll
    for (int j = 0; j < BM / 32; j++) {
      const int cb = j * 256 + w * 64;
      const int c = cb + lane;
      const int r = c >> 3;
      const int kc = (c & 7) ^ (r & 7);
      const ushort* src = Ag + (size_t)r * K + kt + kc * 8;
      const short* ld = sm + cb * 8;
      uint32_t m0v = __builtin_amdgcn_readfirstlane((uint32_t)(uintptr_t)ld);
      asm volatile("s_mov_b32 m0, %0\n\t"
                   "global_load_lds_dwordx4 %1, off\n\t"
                   :: "s"(m0v), "v"(src) : "memory");
    }
#pragma unroll
    for (int j = 0; j < BN / 32; j++) {
      const int cb = j * 256 + w * 64;
      const int c = cb + lane;
      const int r = c >> 3;
      const int kc = (c & 7) ^ (r & 7);
      const ushort* src = Bg + (size_t)r * K + kt + kc * 8;
      const short* ld = sm + (BM * 8 + cb) * 8;
      uint32_t m0v = __builtin_amdgcn_readfirstlane((uint32_t)(uintptr_t)ld);
      asm volatile("s_mov_b32 m0, %0\n\t"
                   "global_load_lds_dwordx4 %1, off\n\t"
                   :: "s"(m0v), "v"(src) : "memory");
    }
    asm volatile("s_waitcnt vmcnt(0)" ::: "memory");
    __syncthreads();

#pragma unroll
    for (int s = 0; s < 2; s++) {
      bf16x8 af[FM];
#pragma unroll
      for (int mi = 0; mi < FM; mi++) {
        const int p = wr * (BM / WR) + mi * 16 + (lane & 15);
        const int ch = (s * 4 + (lane >> 4)) ^ (p & 7);
        af[mi] = *(const bf16x8*)(sm + p * 64 + ch * 8);
      }
#pragma unroll
      for (int ni = 0; ni < FN; ni++) {
        const int q = wc * (BN / WC) + ni * 16 + (lane & 15);
        const int ch = (s * 4 + (lane >> 4)) ^ (q & 7);
        bf16x8 bfv = *(const bf16x8*)(sm + BM * 64 + q * 64 + ch * 8);
#pragma unroll
        for (int mi = 0; mi < FM; mi++)
          acc[mi][ni] = __builtin_amdgcn_mfma_f32_16x16x32_bf16(
              af[mi], bfv, acc[mi][ni], 0, 0, 0);
      }
    }
    __syncthreads();
  }

  const int colb = n0 + wc * (BN / WC) + (lane & 15);
  const int rowb = m0 + wr * (BM / WR) + ((lane >> 4) << 2);
#pragma unroll
  for (int ni = 0; ni < FN; ni++) {
    const float bv = bias[colb + ni * 16];
#pragma unroll
    for (int mi = 0; mi < FM; mi++) {
#pragma unroll
      for (int r = 0; r < 4; r++) {
        float v = acc[mi][ni][r] + bv;
        if (RELU) v = fmaxf(v, 0.0f);
        const size_t off = (size_t)(rowb + mi * 16 + r) * N + colb + ni * 16;
        if (WF32) Cf[off] = v;
        if (WB16) {
          bf16 t = __float2bfloat16(v);
          Cb[off] = *(ushort*)&t;
        }
      }
    }
  }
}

// ---------------------------------------------------------------------------
// f32 -> bf16 convert, 8 elems/thread, grid-stride
// ---------------------------------------------------------------------------
__global__ void cvt_bf16_kernel(const float* __restrict__ src,
                                ushort* __restrict__ dst, long n8) {
  long i = (long)blockIdx.x * blockDim.x + threadIdx.x;
  const long stride = (long)gridDim.x * blockDim.x;
  for (; i < n8; i += stride) {
    float4 v0 = ((const float4*)src)[i * 2];
    float4 v1 = ((const float4*)src)[i * 2 + 1];
    float a[8] = {v0.x, v0.y, v0.z, v0.w, v1.x, v1.y, v1.z, v1.w};
    uint h[8];
#pragma unroll
    for (int c = 0; c < 8; c++) {
      bf16 b = __float2bfloat16(a[c]);
      h[c] = *(ushort*)&b;
    }
    uint4 o;
    o.x = h[0] | (h[1] << 16);
    o.y = h[2] | (h[3] << 16);
    o.z = h[4] | (h[5] << 16);
    o.w = h[6] | (h[7] << 16);
    ((uint4*)dst)[i] = o;
  }
}

// ---------------------------------------------------------------------------
// Transposing convert: src (R x C f32) -> dst (C x R bf16)
// ---------------------------------------------------------------------------
__global__ __launch_bounds__(256) void tconv_kernel(
    const float* __restrict__ src, ushort* __restrict__ dst, int R, int C) {
  __shared__ float t[32][33];
  const int c0 = blockIdx.x * 32, r0 = blockIdx.y * 32;
  const int tx = threadIdx.x & 31, ty = threadIdx.x >> 5;
#pragma unroll
  for (int i = 0; i < 32; i += 8)
    t[ty + i][tx] = src[(size_t)(r0 + ty + i) * C + c0 + tx];
  __syncthreads();
#pragma unroll
  for (int i = 0; i < 32; i += 8) {
    bf16 b = __float2bfloat16(t[tx][ty + i]);
    dst[(size_t)(c0 + ty + i) * R + r0 + tx] = *(ushort*)&b;
  }
}

// ---------------------------------------------------------------------------
// Row squared-norm (rows of width 64)
// ---------------------------------------------------------------------------
__global__ void rownorm64_kernel(const float* __restrict__ v,
                                 float* __restrict__ out, int rows) {
  int r = blockIdx.x * blockDim.x + threadIdx.x;
  if (r >= rows) return;
  const float* p = v + (size_t)r * 64;
  float s = 0.0f;
#pragma unroll 8
  for (int k = 0; k < 64; k++) {
    float q = __fmul_rn(p[k], p[k]);
    s = __fadd_rn(s, q);
  }
  out[r] = s;
}

// ---------------------------------------------------------------------------
// VQ argmin via MFMA. d'_j = cn[j] - 2 * <z[r], c[j]>  (zn dropped: row-const)
// ---------------------------------------------------------------------------
#define AM_CHUNK 2048
__global__ __launch_bounds__(256) void vq_argmin_mfma(
    const ushort* __restrict__ z16, const ushort* __restrict__ cb16,
    const float* __restrict__ cn, float2* __restrict__ partials) {
  const int tid = threadIdx.x;
  const int lane = tid & 63;
  const int w = tid >> 6;
  const int r0 = blockIdx.x * 64 + w * 16;
  const int c0 = blockIdx.y * AM_CHUNK;

  const ushort* zrow =
      z16 + (size_t)(r0 + (lane & 15)) * 64 + ((lane >> 4) * 8);
  const bf16x8 a0 = *(const bf16x8*)zrow;
  const bf16x8 a1 = *(const bf16x8*)(zrow + 32);

  float best[4];
  int bidx[4];
#pragma unroll
  for (int r = 0; r < 4; r++) {
    best[r] = 3.402823466e38f;
    bidx[r] = 0;
  }

  for (int t = 0; t < AM_CHUNK / 16; t++) {
    const int j = c0 + t * 16 + (lane & 15);
    const ushort* crow = cb16 + (size_t)j * 64 + ((lane >> 4) * 8);
    const bf16x8 b0 = *(const bf16x8*)crow;
    const bf16x8 b1 = *(const bf16x8*)(crow + 32);
    f32x4 acc = {0.0f, 0.0f, 0.0f, 0.0f};
    acc = __builtin_amdgcn_mfma_f32_16x16x32_bf16(a0, b0, acc, 0, 0, 0);
    acc = __builtin_amdgcn_mfma_f32_16x16x32_bf16(a1, b1, acc, 0, 0, 0);
    const float cnv = cn[j];
#pragma unroll
    for (int r = 0; r < 4; r++) {
      const float d = fmaf(-2.0f, acc[r], cnv);
      if (d < best[r]) {
        best[r] = d;
        bidx[r] = j;
      }
    }
  }

#pragma unroll
  for (int m = 1; m < 16; m <<= 1) {
#pragma unroll
    for (int r = 0; r < 4; r++) {
      const float ov = __shfl_xor(best[r], m, 64);
      const int oi = __shfl_xor(bidx[r], m, 64);
      if (ov < best[r] || (ov == best[r] && oi < bidx[r])) {
        best[r] = ov;
        bidx[r] = oi;
      }
    }
  }
  if ((lane & 15) == 0) {
#pragma unroll
    for (int r = 0; r < 4; r++) {
      const int row = r0 + ((lane >> 4) << 2) + r;
      partials[(size_t)row * (NC / AM_CHUNK) + blockIdx.y] =
          make_float2(best[r], __int_as_float(bidx[r]));
    }
  }
}

__global__ void argmin_reduce_kernel(const float2* __restrict__ partials,
                                     int* __restrict__ idx) {
  const int row = blockIdx.x * 256 + threadIdx.x;
  float2 best = partials[(size_t)row * (NC / AM_CHUNK)];
#pragma unroll
  for (int c = 1; c < NC / AM_CHUNK; c++) {
    const float2 p = partials[(size_t)row * (NC / AM_CHUNK) + c];
    if (p.x < best.x) best = p;
  }
  idx[row] = __float_as_int(best.y);
}

// ---------------------------------------------------------------------------
// z output: out0[r] = z_e[r] + (codebook[idx[r]] - z_e[r]) in f32
// ---------------------------------------------------------------------------
__global__ void gather_z_kernel(const float* __restrict__ z_e,
                                const float* __restrict__ cb,
                                const int* __restrict__ idx,
                                float* __restrict__ out0) {
  int t = blockIdx.x * 256 + threadIdx.x;
  int row = t >> 4;
  int c4 = t & 15;
  int code = idx[row];
  float4 q = *reinterpret_cast<const float4*>(&cb[(size_t)code * 64 + c4 * 4]);
  float4 e = *reinterpret_cast<const float4*>(&z_e[(size_t)row * 64 + c4 * 4]);
  float4 o;
  o.x = __fadd_rn(e.x, __fsub_rn(q.x, e.x));
  o.y = __fadd_rn(e.y, __fsub_rn(q.y, e.y));
  o.z = __fadd_rn(e.z, __fsub_rn(q.z, e.z));
  o.w = __fadd_rn(e.w, __fsub_rn(q.w, e.w));
  *reinterpret_cast<float4*>(&out0[(size_t)row * 64 + c4 * 4]) = o;
}

__global__ void gather_recon_kernel(const float* __restrict__ table,
                                    const int* __restrict__ idx,
                                    float* __restrict__ out1) {
  int row = blockIdx.x >> 2;
  int q = blockIdx.x & 3;
  int c4 = q * 256 + threadIdx.x;
  int code = idx[row];
  float4 v = *reinterpret_cast<const float4*>(
      &table[(size_t)code * 4096 + (size_t)c4 * 4]);
  *reinterpret_cast<float4*>(&out1[(size_t)row * 4096 + (size_t)c4 * 4]) = v;
}

// ---------------------------------------------------------------------------
extern "C" void kernel_launch(void* const* d_in, const int* in_sizes, int n_in,
                              void* d_out, int out_size, void* d_ws,
                              size_t ws_size, hipStream_t stream) {
  const float* x   = (const float*)d_in[0];
  const float* W1  = (const float*)d_in[1];
  const float* b1  = (const float*)d_in[2];
  const float* W2  = (const float*)d_in[3];
  const float* b2  = (const float*)d_in[4];
  const float* cb  = (const float*)d_in[5];
  const float* dW1 = (const float*)d_in[6];
  const float* db1 = (const float*)d_in[7];
  const float* dW2 = (const float*)d_in[8];
  const float* db2 = (const float*)d_in[9];

  float* out0 = (float*)d_out;                      // z: 16384 x 64 (4 MB)
  char* o1b = (char*)d_out + (size_t)BROWS * BOT * 4;  // x_recon region 256 MB
  float* out1 = (float*)o1b;

  // out1-region scratch (all dead before gather_recon overwrites out1):
  ushort* x16   = (ushort*)(o1b);                    // [0,128M)   a..GEMM1
  ushort* W1t   = (ushort*)(o1b + 128 * MB);         // [128,144M) ..GEMM1
  ushort* h16   = (ushort*)(o1b + 144 * MB);         // [144,208M) GEMM1..GEMM2
  float*  z_e   = (float*)(o1b + 64 * MB);           // [64,68M)   GEMM2..gather
  ushort* z16   = (ushort*)(o1b + 68 * MB);          // [68,70M)   GEMM2..argmin
  ushort* cb16  = (ushort*)(o1b + 70 * MB);          // [70,71M)   ..dec-hidden
  float*  cn    = (float*)(o1b + 71 * MB);           // 32 KB      ..argmin
  float2* parts = (float2*)(o1b + 71 * MB + 524288); // 512 KB     argmin..red
  ushort* W2t   = (ushort*)(o1b + 72 * MB);          // 256 KB     ..GEMM2
  ushort* dW1t  = (ushort*)(o1b + 73 * MB);          // 256 KB     ..dec-hidden
  ushort* ht16  = (ushort*)(o1b);                    // [0,32M)    dec..table
  ushort* dW2t  = (ushort*)(o1b + 32 * MB);          // [32,64M)   ..table

  // workspace: table + idx only (high-water ~128.1 MB)
  char* wsb = (char*)d_ws;
  float* table = (float*)wsb;                        // [0,128M)   table..gather
  int*   idxb  = (int*)(wsb + 128 * MB);             // 64 KB      red..gathers

  dim3 blk(256);

  // a. x -> bf16
  cvt_bf16_kernel<<<dim3(2048), blk, 0, stream>>>(x, x16,
                                                  (long)BROWS * INDIM / 8);
  // b. W1^T -> bf16 (2048 x 4096)
  tconv_kernel<<<dim3(HID / 32, INDIM / 32), blk, 0, stream>>>(W1, W1t, INDIM,
                                                               HID);
  // c. GEMM1: h = relu(x @ W1 + b1), bf16 out   M=16384 N=2048 K=4096
  gemm256<true, false, true>
      <<<dim3(HID / 256, BROWS / 256), dim3(512), 0, stream>>>(
          x16, W1t, b1, nullptr, h16, BROWS, HID, INDIM);
  // d. W2^T -> bf16 (64 x 2048)
  tconv_kernel<<<dim3(BOT / 32, HID / 32), blk, 0, stream>>>(W2, W2t, HID,
                                                             BOT);
  // e. GEMM2: z_e = h @ W2 + b2, f32 + bf16 out  M=16384 N=64 K=2048
  gemm_bt<64, 64, 2, 2, false, true, true>
      <<<dim3(1, BROWS / 64), blk, 0, stream>>>(h16, W2t, b2, z_e, z16, BROWS,
                                                BOT, HID);
  // f. codebook -> bf16
  cvt_bf16_kernel<<<dim3(256), blk, 0, stream>>>(cb, cb16, (long)NC * BOT / 8);
  // g. cn = ||c||^2
  rownorm64_kernel<<<dim3(NC / 256), blk, 0, stream>>>(cb, cn, NC);
  // h. argmin (MFMA, 4 code chunks)
  vq_argmin_mfma<<<dim3(BROWS / 64, NC / AM_CHUNK), blk, 0, stream>>>(
      z16, cb16, cn, parts);
  // i. reduce chunks
  argmin_reduce_kernel<<<dim3(BROWS / 256), blk, 0, stream>>>(parts, idxb);
  // j. dW1^T -> bf16 (2048 x 64)
  tconv_kernel<<<dim3(HID / 32, BOT / 32), blk, 0, stream>>>(dW1, dW1t, BOT,
                                                             HID);
  // k. decoder hidden: ht = relu(cb @ dW1 + db1), bf16 out M=8192 N=2048 K=64
  gemm_bt<128, 128, 2, 2, true, false, true>
      <<<dim3(HID / 128, NC / 128), blk, 0, stream>>>(cb16, dW1t, db1, nullptr,
                                                      ht16, NC, HID, BOT);
  // l. dW2^T -> bf16 (4096 x 2048)
  tconv_kernel<<<dim3(INDIM / 32, HID / 32), blk, 0, stream>>>(dW2, dW2t, HID,
                                                               INDIM);
  // m. table = ht @ dW2 + db2, f32 out  M=8192 N=4096 K=2048
  gemm256<false, true, false>
      <<<dim3(INDIM / 256, NC / 256), dim3(512), 0, stream>>>(
          ht16, dW2t, db2, table, nullptr, NC, INDIM, HID);
  // n. z output
  gather_z_kernel<<<dim3(BROWS * 16 / 256), blk, 0, stream>>>(z_e, cb, idxb,
                                                              out0);
  // o. x_recon output
  gather_recon_kernel<<<dim3(BROWS * 4), blk, 0, stream>>>(table, idxb, out1);
}